// Round 1
// baseline (3831.688 us; speedup 1.0000x reference)
//
#include <hip/hip_runtime.h>
#include <math.h>

#define N_NODES   100000
#define N_EDGES   1600000
#define IN_DIM    256
#define OUT_DIM   32
#define HEADS     4
#define C_DIM     128      // OUT_DIM*HEADS
#define EDGE_DIM  64
#define NUM_ETY   8
#define NEG_SLOPE 0.2f
#define NPB       8        // nodes per block in the dense kernel

// ---- ordered-uint encoding for float atomicMax (handles negatives) ----
__device__ __forceinline__ unsigned int fkey(float f) {
    unsigned int u = __float_as_uint(f);
    return (u & 0x80000000u) ? ~u : (u | 0x80000000u);
}
__device__ __forceinline__ float fkey_dec(unsigned int k) {
    unsigned int u = (k & 0x80000000u) ? (k ^ 0x80000000u) : ~k;
    return __uint_as_float(u);
}

// K0: init segmax/segsum; block 0 computes h_e_type[8][4]
__global__ void k0_init(unsigned int* __restrict__ segmax, float* __restrict__ segsum,
                        const float* __restrict__ edge_emb, const float* __restrict__ Wr,
                        const float* __restrict__ a_e, float* __restrict__ h_et) {
    int i = blockIdx.x * blockDim.x + threadIdx.x;
    if (i < N_NODES * HEADS) {
        segmax[i] = fkey(-INFINITY);
        segsum[i] = 0.0f;
    }
    if (blockIdx.x == 0 && threadIdx.x < NUM_ETY * HEADS) {
        int t = threadIdx.x / HEADS, hh = threadIdx.x % HEADS;
        float acc = 0.f;
        for (int f = 0; f < EDGE_DIM; ++f) {
            float et = 0.f;
            for (int e = 0; e < EDGE_DIM; ++e)
                et += edge_emb[t * EDGE_DIM + e] *
                      Wr[(t * EDGE_DIM + e) * (HEADS * EDGE_DIM) + hh * EDGE_DIM + f];
            acc += a_e[hh * EDGE_DIM + f] * et;
        }
        h_et[t * HEADS + hh] = acc;
    }
}

// K1: per 8 nodes: emb = h@W (layout [n, h*32+d]), h_l, h_r, out = h@resW + b
__global__ __launch_bounds__(256) void k1_node(
    const float* __restrict__ h, const float* __restrict__ W,
    const float* __restrict__ resW, const float* __restrict__ resb,
    const float* __restrict__ a_l, const float* __restrict__ a_r,
    float* __restrict__ emb, float* __restrict__ hl, float* __restrict__ hr,
    float* __restrict__ out) {
    __shared__ float hrow[NPB][IN_DIM];
    const int t  = threadIdx.x;
    const int n0 = blockIdx.x * NPB;
    for (int j = 0; j < NPB; ++j)
        hrow[j][t] = h[(size_t)(n0 + j) * IN_DIM + t];
    __syncthreads();

    const bool isEmb = t < C_DIM;
    const int  c = isEmb ? t : (t - C_DIM);
    const float* __restrict__ M = isEmb ? W : resW;

    float acc[NPB];
#pragma unroll
    for (int j = 0; j < NPB; ++j) acc[j] = 0.f;
    for (int k = 0; k < IN_DIM; ++k) {
        float w = M[k * C_DIM + c];
#pragma unroll
        for (int j = 0; j < NPB; ++j) acc[j] += hrow[j][k] * w;
    }

    if (isEmb) {
        // waves 0,1 fully in this branch (t<128) -> shuffles are whole-wave safe
        const float al = a_l[c], ar = a_r[c];
        const int hh = c >> 5;                 // c = hh*32 + d
#pragma unroll
        for (int j = 0; j < NPB; ++j) {
            float v = acc[j];
            emb[(size_t)(n0 + j) * C_DIM + c] = v;
            float pl = al * v, pr = ar * v;
#pragma unroll
            for (int m = 16; m >= 1; m >>= 1) { // reduce within 32-lane group
                pl += __shfl_xor(pl, m);
                pr += __shfl_xor(pr, m);
            }
            if ((t & 31) == 0) {
                hl[(n0 + j) * HEADS + hh] = pl;
                hr[(n0 + j) * HEADS + hh] = pr;
            }
        }
    } else {
        const float b = resb[c];
#pragma unroll
        for (int j = 0; j < NPB; ++j)
            out[(size_t)(n0 + j) * C_DIM + c] = acc[j] + b;
    }
}

// K2: att logits + leaky relu + atomic segment max over col
__global__ void k2_att(const int* __restrict__ row, const int* __restrict__ col,
                       const int* __restrict__ ety,
                       const float* __restrict__ hl, const float* __restrict__ hr,
                       const float* __restrict__ het,
                       float* __restrict__ att, unsigned int* __restrict__ segmax) {
    int e = blockIdx.x * blockDim.x + threadIdx.x;
    if (e >= N_EDGES) return;
    int r = row[e], c = col[e], ty = ety[e];
    float4 l  = *(const float4*)&hl[r * 4];
    float4 rr = *(const float4*)&hr[c * 4];
    float4 te = *(const float4*)&het[ty * 4];
    float a0 = l.x + rr.x + te.x;
    float a1 = l.y + rr.y + te.y;
    float a2 = l.z + rr.z + te.z;
    float a3 = l.w + rr.w + te.w;
    a0 = a0 > 0.f ? a0 : NEG_SLOPE * a0;
    a1 = a1 > 0.f ? a1 : NEG_SLOPE * a1;
    a2 = a2 > 0.f ? a2 : NEG_SLOPE * a2;
    a3 = a3 > 0.f ? a3 : NEG_SLOPE * a3;
    *(float4*)&att[e * 4] = make_float4(a0, a1, a2, a3);
    atomicMax(&segmax[c * 4 + 0], fkey(a0));
    atomicMax(&segmax[c * 4 + 1], fkey(a1));
    atomicMax(&segmax[c * 4 + 2], fkey(a2));
    atomicMax(&segmax[c * 4 + 3], fkey(a3));
}

// K3: ex = exp(att - max), atomic segment sum
__global__ void k3_exp(const int* __restrict__ col, float* __restrict__ att,
                       const unsigned int* __restrict__ segmax, float* __restrict__ segsum) {
    int e = blockIdx.x * blockDim.x + threadIdx.x;
    if (e >= N_EDGES) return;
    int c = col[e];
    float4 a = *(const float4*)&att[e * 4];
    uint4 mk = *(const uint4*)&segmax[c * 4];
    float e0 = expf(a.x - fkey_dec(mk.x));
    float e1 = expf(a.y - fkey_dec(mk.y));
    float e2 = expf(a.z - fkey_dec(mk.z));
    float e3 = expf(a.w - fkey_dec(mk.w));
    *(float4*)&att[e * 4] = make_float4(e0, e1, e2, e3);
    atomicAdd(&segsum[c * 4 + 0], e0);
    atomicAdd(&segsum[c * 4 + 1], e1);
    atomicAdd(&segsum[c * 4 + 2], e2);
    atomicAdd(&segsum[c * 4 + 3], e3);
}

// K4: alpha = ex/segsum[col]; out[col, d*4+h] += emb[row, h*32+d]*alpha[h]
__global__ __launch_bounds__(256) void k4_agg(
    const int* __restrict__ row, const int* __restrict__ col,
    const float* __restrict__ ex, const float* __restrict__ segsum,
    const float* __restrict__ emb, float* __restrict__ out) {
    int gid = blockIdx.x * blockDim.x + threadIdx.x;
    int e = gid >> 5;
    int d = gid & 31;
    if (e >= N_EDGES) return;
    int r = row[e], c = col[e];
    float4 ex4 = *(const float4*)&ex[e * 4];
    float4 s4  = *(const float4*)&segsum[c * 4];
    float al0 = ex4.x / s4.x, al1 = ex4.y / s4.y, al2 = ex4.z / s4.z, al3 = ex4.w / s4.w;
    const float* er = &emb[(size_t)r * C_DIM];
    float m0 = er[0 * 32 + d];
    float m1 = er[1 * 32 + d];
    float m2 = er[2 * 32 + d];
    float m3 = er[3 * 32 + d];
    float* o = &out[(size_t)c * C_DIM + d * 4];
    atomicAdd(o + 0, m0 * al0);
    atomicAdd(o + 1, m1 * al1);
    atomicAdd(o + 2, m2 * al2);
    atomicAdd(o + 3, m3 * al3);
}

// K5: in-place ELU
__global__ void k5_elu(float* __restrict__ out) {
    int i = blockIdx.x * blockDim.x + threadIdx.x;
    if (i < N_NODES * C_DIM) {
        float x = out[i];
        out[i] = x > 0.f ? x : expm1f(x);
    }
}

extern "C" void kernel_launch(void* const* d_in, const int* in_sizes, int n_in,
                              void* d_out, int out_size, void* d_ws, size_t ws_size,
                              hipStream_t stream) {
    const float* h        = (const float*)d_in[0];
    const float* W        = (const float*)d_in[1];
    const float* edge_emb = (const float*)d_in[2];
    const float* Wr       = (const float*)d_in[3];
    const float* a_l      = (const float*)d_in[4];
    const float* a_r      = (const float*)d_in[5];
    const float* a_e      = (const float*)d_in[6];
    const float* res_W    = (const float*)d_in[7];
    const float* res_b    = (const float*)d_in[8];
    const int*   row      = (const int*)d_in[9];
    const int*   col      = (const int*)d_in[10];
    const int*   etype    = (const int*)d_in[11];
    float* out = (float*)d_out;

    // workspace layout (floats)
    float* ws = (float*)d_ws;
    float*        ws_emb    = ws;                               // N*128
    float*        ws_hl     = ws_emb + (size_t)N_NODES * C_DIM; // N*4
    float*        ws_hr     = ws_hl + (size_t)N_NODES * HEADS;  // N*4
    unsigned int* ws_segmax = (unsigned int*)(ws_hr + (size_t)N_NODES * HEADS); // N*4
    float*        ws_segsum = (float*)(ws_segmax + (size_t)N_NODES * HEADS);    // N*4
    float*        ws_ex     = ws_segsum + (size_t)N_NODES * HEADS;              // E*4
    float*        ws_het    = ws_ex + (size_t)N_EDGES * HEADS;                  // 32

    k0_init<<<(N_NODES * HEADS + 255) / 256, 256, 0, stream>>>(
        ws_segmax, ws_segsum, edge_emb, Wr, a_e, ws_het);

    k1_node<<<N_NODES / NPB, 256, 0, stream>>>(
        h, W, res_W, res_b, a_l, a_r, ws_emb, ws_hl, ws_hr, out);

    k2_att<<<(N_EDGES + 255) / 256, 256, 0, stream>>>(
        row, col, etype, ws_hl, ws_hr, ws_het, ws_ex, ws_segmax);

    k3_exp<<<(N_EDGES + 255) / 256, 256, 0, stream>>>(
        col, ws_ex, ws_segmax, ws_segsum);

    k4_agg<<<(N_EDGES * 32 + 255) / 256, 256, 0, stream>>>(
        row, col, ws_ex, ws_segsum, ws_emb, out);

    k5_elu<<<(N_NODES * C_DIM + 255) / 256, 256, 0, stream>>>(out);
}

// Round 2
// 868.195 us; speedup vs baseline: 4.4134x; 4.4134x over previous
//
#include <hip/hip_runtime.h>
#include <math.h>

#define N_NODES   100000
#define N_EDGES   1600000
#define IN_DIM    256
#define OUT_DIM   32
#define HEADS     4
#define C_DIM     128      // OUT_DIM*HEADS
#define EDGE_DIM  64
#define NUM_ETY   8
#define NEG_SLOPE 0.2f
#define NPB       8        // nodes per block in the dense kernel
#define NBLK_SCAN 391      // ceil(N_NODES/256)

// ---------------------------------------------------------------------------
// kz: zero the degree counters; block 0 also computes h_e_type[8][4]
__global__ void kz_init(unsigned int* __restrict__ counts,
                        const float* __restrict__ edge_emb, const float* __restrict__ Wr,
                        const float* __restrict__ a_e, float* __restrict__ h_et) {
    int i = blockIdx.x * blockDim.x + threadIdx.x;
    if (i < N_NODES) counts[i] = 0u;
    if (blockIdx.x == 0 && threadIdx.x < NUM_ETY * HEADS) {
        int t = threadIdx.x / HEADS, hh = threadIdx.x % HEADS;
        float acc = 0.f;
        for (int f = 0; f < EDGE_DIM; ++f) {
            float et = 0.f;
            for (int e = 0; e < EDGE_DIM; ++e)
                et += edge_emb[t * EDGE_DIM + e] *
                      Wr[(t * EDGE_DIM + e) * (HEADS * EDGE_DIM) + hh * EDGE_DIM + f];
            acc += a_e[hh * EDGE_DIM + f] * et;
        }
        h_et[t * HEADS + hh] = acc;
    }
}

// ---------------------------------------------------------------------------
// K1: per 8 nodes: emb = h@W (layout [n, h*32+d]), h_l, h_r, out = h@resW + b
__global__ __launch_bounds__(256) void k1_node(
    const float* __restrict__ h, const float* __restrict__ W,
    const float* __restrict__ resW, const float* __restrict__ resb,
    const float* __restrict__ a_l, const float* __restrict__ a_r,
    float* __restrict__ emb, float* __restrict__ hl, float* __restrict__ hr,
    float* __restrict__ out) {
    __shared__ float hrow[NPB][IN_DIM];
    const int t  = threadIdx.x;
    const int n0 = blockIdx.x * NPB;
    for (int j = 0; j < NPB; ++j)
        hrow[j][t] = h[(size_t)(n0 + j) * IN_DIM + t];
    __syncthreads();

    const bool isEmb = t < C_DIM;
    const int  c = isEmb ? t : (t - C_DIM);
    const float* __restrict__ M = isEmb ? W : resW;

    float acc[NPB];
#pragma unroll
    for (int j = 0; j < NPB; ++j) acc[j] = 0.f;
    for (int k = 0; k < IN_DIM; ++k) {
        float w = M[k * C_DIM + c];
#pragma unroll
        for (int j = 0; j < NPB; ++j) acc[j] += hrow[j][k] * w;
    }

    if (isEmb) {
        const float al = a_l[c], ar = a_r[c];
        const int hh = c >> 5;                 // c = hh*32 + d
#pragma unroll
        for (int j = 0; j < NPB; ++j) {
            float v = acc[j];
            emb[(size_t)(n0 + j) * C_DIM + c] = v;
            float pl = al * v, pr = ar * v;
#pragma unroll
            for (int m = 16; m >= 1; m >>= 1) {
                pl += __shfl_xor(pl, m);
                pr += __shfl_xor(pr, m);
            }
            if ((t & 31) == 0) {
                hl[(n0 + j) * HEADS + hh] = pl;
                hr[(n0 + j) * HEADS + hh] = pr;
            }
        }
    } else {
        const float b = resb[c];
#pragma unroll
        for (int j = 0; j < NPB; ++j)
            out[(size_t)(n0 + j) * C_DIM + c] = acc[j] + b;
    }
}

// ---------------------------------------------------------------------------
// histogram of destination degrees
__global__ void b1_hist(const int* __restrict__ col, unsigned int* __restrict__ counts) {
    int e = blockIdx.x * blockDim.x + threadIdx.x;
    if (e < N_EDGES) atomicAdd(&counts[col[e]], 1u);
}

// two-level exclusive scan: per-block scan
__global__ __launch_bounds__(256) void bscan1(const unsigned int* __restrict__ counts,
                                              unsigned int* __restrict__ offs,
                                              unsigned int* __restrict__ bsum) {
    __shared__ unsigned int s[256];
    int t = threadIdx.x;
    int g = blockIdx.x * 256 + t;
    unsigned int v = (g < N_NODES) ? counts[g] : 0u;
    s[t] = v;
    __syncthreads();
    for (int off = 1; off < 256; off <<= 1) {
        unsigned int x = (t >= off) ? s[t - off] : 0u;
        __syncthreads();
        s[t] += x;
        __syncthreads();
    }
    if (g < N_NODES) offs[g] = s[t] - v;   // exclusive within block
    if (t == 255) bsum[blockIdx.x] = s[255];
}

__global__ __launch_bounds__(512) void bscan2(unsigned int* __restrict__ bsum) {
    __shared__ unsigned int s[512];
    int t = threadIdx.x;
    unsigned int v = (t < NBLK_SCAN) ? bsum[t] : 0u;
    s[t] = v;
    __syncthreads();
    for (int off = 1; off < 512; off <<= 1) {
        unsigned int x = (t >= off) ? s[t - off] : 0u;
        __syncthreads();
        s[t] += x;
        __syncthreads();
    }
    if (t < NBLK_SCAN) bsum[t] = s[t] - v; // exclusive
}

__global__ void bscan3(unsigned int* __restrict__ offs, const unsigned int* __restrict__ bsum,
                       unsigned int* __restrict__ cursor) {
    int g = blockIdx.x * blockDim.x + threadIdx.x;
    if (g < N_NODES) {
        unsigned int o = offs[g] + bsum[g >> 8];
        offs[g] = o;
        cursor[g] = o;
    }
    if (g == 0) offs[N_NODES] = N_EDGES;
}

// ---------------------------------------------------------------------------
// scatter: place each edge in its destination bucket; precompute leaky logit
__global__ void b4_scatter(const int* __restrict__ row, const int* __restrict__ col,
                           const int* __restrict__ ety,
                           const float* __restrict__ hl, const float* __restrict__ hr,
                           const float* __restrict__ het,
                           unsigned int* __restrict__ cursor,
                           float4* __restrict__ plog, int* __restrict__ prow) {
    int e = blockIdx.x * blockDim.x + threadIdx.x;
    if (e >= N_EDGES) return;
    int r = row[e], c = col[e], ty = ety[e];
    unsigned int pos = atomicAdd(&cursor[c], 1u);
    float4 l  = *(const float4*)&hl[r * 4];
    float4 rr = *(const float4*)&hr[c * 4];
    float4 te = *(const float4*)&het[ty * 4];
    float a0 = l.x + rr.x + te.x;
    float a1 = l.y + rr.y + te.y;
    float a2 = l.z + rr.z + te.z;
    float a3 = l.w + rr.w + te.w;
    a0 = a0 > 0.f ? a0 : NEG_SLOPE * a0;
    a1 = a1 > 0.f ? a1 : NEG_SLOPE * a1;
    a2 = a2 > 0.f ? a2 : NEG_SLOPE * a2;
    a3 = a3 > 0.f ? a3 : NEG_SLOPE * a3;
    plog[pos] = make_float4(a0, a1, a2, a3);
    prow[pos] = r;
}

// ---------------------------------------------------------------------------
// fused per-node softmax + aggregation + residual + ELU. One wave per node.
__device__ __forceinline__ void online_upd(float& m, float& s, float l) {
    float nm = fmaxf(m, l);
    s = s * __expf(m - nm) + __expf(l - nm);
    m = nm;
}

__global__ __launch_bounds__(256) void k_fused(
    const unsigned int* __restrict__ offs, const float4* __restrict__ plog,
    const int* __restrict__ prow, const float* __restrict__ emb,
    float* __restrict__ out) {
    __shared__ float alds[4][16][4];
    __shared__ int   rlds[4][16];
    const int w    = threadIdx.x >> 6;
    const int lane = threadIdx.x & 63;
    const int c    = blockIdx.x * 4 + w;
    if (c >= N_NODES) return;

    const unsigned int start = offs[c], end = offs[c + 1];

    // phase A: online softmax stats per lane, stride 64 over the bucket
    float m0 = -1e30f, m1 = -1e30f, m2 = -1e30f, m3 = -1e30f;
    float s0 = 0.f, s1 = 0.f, s2 = 0.f, s3 = 0.f;
    for (unsigned int i = start + lane; i < end; i += 64) {
        float4 L = plog[i];
        online_upd(m0, s0, L.x);
        online_upd(m1, s1, L.y);
        online_upd(m2, s2, L.z);
        online_upd(m3, s3, L.w);
    }
    // wave reduce (m,s) per head
#pragma unroll
    for (int off = 32; off >= 1; off >>= 1) {
        float mo, so, nm;
        mo = __shfl_xor(m0, off); so = __shfl_xor(s0, off);
        nm = fmaxf(m0, mo); s0 = s0 * __expf(m0 - nm) + so * __expf(mo - nm); m0 = nm;
        mo = __shfl_xor(m1, off); so = __shfl_xor(s1, off);
        nm = fmaxf(m1, mo); s1 = s1 * __expf(m1 - nm) + so * __expf(mo - nm); m1 = nm;
        mo = __shfl_xor(m2, off); so = __shfl_xor(s2, off);
        nm = fmaxf(m2, mo); s2 = s2 * __expf(m2 - nm) + so * __expf(mo - nm); m2 = nm;
        mo = __shfl_xor(m3, off); so = __shfl_xor(s3, off);
        nm = fmaxf(m3, mo); s3 = s3 * __expf(m3 - nm) + so * __expf(mo - nm); m3 = nm;
    }
    const bool hasE = end > start;
    const float i0 = hasE ? 1.f / s0 : 0.f;
    const float i1 = hasE ? 1.f / s1 : 0.f;
    const float i2 = hasE ? 1.f / s2 : 0.f;
    const float i3 = hasE ? 1.f / s3 : 0.f;

    // phase B: aggregate. lane reads emb cols lane and lane+64 (coalesced).
    // emb col l -> head h=l>>5, d=l&31 -> out channel c0 = d*4+h ; col l+64 -> c0+2
    const int h0 = lane >> 5;
    const int c0 = ((lane & 31) << 2) | h0;
    float acc0 = 0.f, acc1 = 0.f;

    for (unsigned int base = start; base < end; base += 16) {
        int cnt = (int)min(16u, end - base);
        if (lane < cnt) {
            float4 L = plog[base + lane];
            alds[w][lane][0] = __expf(L.x - m0) * i0;
            alds[w][lane][1] = __expf(L.y - m1) * i1;
            alds[w][lane][2] = __expf(L.z - m2) * i2;
            alds[w][lane][3] = __expf(L.w - m3) * i3;
            rlds[w][lane] = prow[base + lane];
        }
        for (int j = 0; j < cnt; ++j) {
            int r = rlds[w][j];
            float a0 = alds[w][j][h0];
            float a1 = alds[w][j][h0 + 2];
            const float* er = &emb[(size_t)r * C_DIM];
            acc0 = fmaf(a0, er[lane], acc0);
            acc1 = fmaf(a1, er[lane + 64], acc1);
        }
    }

    // residual (already in out) + ELU, single write per element
    size_t ob = (size_t)c * C_DIM;
    float x0 = out[ob + c0] + acc0;
    float x1 = out[ob + c0 + 2] + acc1;
    out[ob + c0]     = x0 > 0.f ? x0 : expm1f(x0);
    out[ob + c0 + 2] = x1 > 0.f ? x1 : expm1f(x1);
}

// ---------------------------------------------------------------------------
extern "C" void kernel_launch(void* const* d_in, const int* in_sizes, int n_in,
                              void* d_out, int out_size, void* d_ws, size_t ws_size,
                              hipStream_t stream) {
    const float* h        = (const float*)d_in[0];
    const float* W        = (const float*)d_in[1];
    const float* edge_emb = (const float*)d_in[2];
    const float* Wr       = (const float*)d_in[3];
    const float* a_l      = (const float*)d_in[4];
    const float* a_r      = (const float*)d_in[5];
    const float* a_e      = (const float*)d_in[6];
    const float* res_W    = (const float*)d_in[7];
    const float* res_b    = (const float*)d_in[8];
    const int*   row      = (const int*)d_in[9];
    const int*   col      = (const int*)d_in[10];
    const int*   etype    = (const int*)d_in[11];
    float* out = (float*)d_out;

    // workspace layout (4-byte units); plog first for 16B alignment
    float* ws = (float*)d_ws;
    float4*       ws_plog  = (float4*)ws;                                   // E*4 floats
    float*        ws_emb   = ws + (size_t)N_EDGES * 4;                      // N*128
    float*        ws_hl    = ws_emb + (size_t)N_NODES * C_DIM;              // N*4
    float*        ws_hr    = ws_hl + (size_t)N_NODES * HEADS;               // N*4
    float*        ws_het   = ws_hr + (size_t)N_NODES * HEADS;               // 32
    unsigned int* ws_offs  = (unsigned int*)(ws_het + 32);                  // N+1
    unsigned int* ws_cur   = ws_offs + (N_NODES + 1);                       // N
    unsigned int* ws_cnt   = ws_cur + N_NODES;                              // N
    unsigned int* ws_bsum  = ws_cnt + N_NODES;                              // NBLK_SCAN
    int*          ws_prow  = (int*)(ws_bsum + NBLK_SCAN);                   // E

    kz_init<<<(N_NODES + 255) / 256, 256, 0, stream>>>(ws_cnt, edge_emb, Wr, a_e, ws_het);

    k1_node<<<N_NODES / NPB, 256, 0, stream>>>(
        h, W, res_W, res_b, a_l, a_r, ws_emb, ws_hl, ws_hr, out);

    b1_hist<<<(N_EDGES + 255) / 256, 256, 0, stream>>>(col, ws_cnt);

    bscan1<<<NBLK_SCAN, 256, 0, stream>>>(ws_cnt, ws_offs, ws_bsum);
    bscan2<<<1, 512, 0, stream>>>(ws_bsum);
    bscan3<<<(N_NODES + 255) / 256, 256, 0, stream>>>(ws_offs, ws_bsum, ws_cur);

    b4_scatter<<<(N_EDGES + 255) / 256, 256, 0, stream>>>(
        row, col, etype, ws_hl, ws_hr, ws_het, ws_cur, ws_plog, ws_prow);

    k_fused<<<(N_NODES + 3) / 4, 256, 0, stream>>>(
        ws_offs, ws_plog, ws_prow, ws_emb, out);
}

// Round 3
// 775.071 us; speedup vs baseline: 4.9437x; 1.1201x over previous
//
#include <hip/hip_runtime.h>
#include <math.h>

#define N_NODES   100000
#define N_EDGES   1600000
#define IN_DIM    256
#define OUT_DIM   32
#define HEADS     4
#define C_DIM     128      // OUT_DIM*HEADS
#define EDGE_DIM  64
#define NUM_ETY   8
#define NEG_SLOPE 0.2f
#define NBLK_SCAN 391      // ceil(N_NODES/256)

typedef __attribute__((ext_vector_type(8))) short s8b;   // 8 bf16 (4 VGPRs)
typedef __attribute__((ext_vector_type(4))) float f32x4; // MFMA accumulator

__device__ __forceinline__ short bf16rne(float x) {
    unsigned int u = __float_as_uint(x);
    unsigned int r = (u + 0x7FFFu + ((u >> 16) & 1u)) >> 16;
    return (short)r;
}

// ---------------------------------------------------------------------------
// kz: zero the degree counters; block 0 also computes h_e_type[8][4]
__global__ void kz_init(unsigned int* __restrict__ counts,
                        const float* __restrict__ edge_emb, const float* __restrict__ Wr,
                        const float* __restrict__ a_e, float* __restrict__ h_et) {
    int i = blockIdx.x * blockDim.x + threadIdx.x;
    if (i < N_NODES) counts[i] = 0u;
    if (blockIdx.x == 0 && threadIdx.x < NUM_ETY * HEADS) {
        int t = threadIdx.x / HEADS, hh = threadIdx.x % HEADS;
        float acc = 0.f;
        for (int f = 0; f < EDGE_DIM; ++f) {
            float et = 0.f;
            for (int e = 0; e < EDGE_DIM; ++e)
                et += edge_emb[t * EDGE_DIM + e] *
                      Wr[(t * EDGE_DIM + e) * (HEADS * EDGE_DIM) + hh * EDGE_DIM + f];
            acc += a_e[hh * EDGE_DIM + f] * et;
        }
        h_et[t * HEADS + hh] = acc;
    }
}

// kw: transpose+convert [W | resW] (fp32, [k][c]) -> Wt bf16 [c][k]
__global__ void kw_prep(const float* __restrict__ W, const float* __restrict__ resW,
                        short* __restrict__ wt) {
    int idx = blockIdx.x * 256 + threadIdx.x;     // 65536 = 256k x 256c
    int k = idx >> 8, c = idx & 255;
    float v = (c < C_DIM) ? W[k * C_DIM + c] : resW[k * C_DIM + (c - C_DIM)];
    wt[c * IN_DIM + k] = bf16rne(v);
}

// ---------------------------------------------------------------------------
// K1 (MFMA): per block: 64 nodes x 256 outcols of h @ [W|resW] in bf16.
// Wave w handles rows w*16..w*16+15, all 256 cols (16 n-frags x 8 k-steps).
// Epilogue: emb store (cols 0..127), out = res + b (cols 128..255), hl/hr.
__global__ __launch_bounds__(256) void k1_mfma(
    const float* __restrict__ h, const short* __restrict__ wt,
    const float* __restrict__ resb,
    const float* __restrict__ a_l, const float* __restrict__ a_r,
    float* __restrict__ emb, float* __restrict__ hl, float* __restrict__ hr,
    float* __restrict__ out) {
    __shared__ short hs[64 * IN_DIM];   // bf16, XOR-swizzled rows
    const int t  = threadIdx.x;
    const int n0 = blockIdx.x * 64;

    // stage h tile -> bf16 LDS. wave-uniform row per iter; swizzle idx^=(row&7)<<3
#pragma unroll
    for (int i = 0; i < 16; ++i) {
        int flat = i * 256 + t;
        int row = flat >> 6, c4 = flat & 63;   // c4*4 = k base
        int rg = n0 + row;
        float4 v = make_float4(0.f, 0.f, 0.f, 0.f);
        if (rg < N_NODES) v = *(const float4*)&h[(size_t)rg * IN_DIM + c4 * 4];
        short4 b4;
        b4.x = bf16rne(v.x); b4.y = bf16rne(v.y);
        b4.z = bf16rne(v.z); b4.w = bf16rne(v.w);
        int idx = (row * IN_DIM + c4 * 4) ^ ((row & 7) << 3);
        *(short4*)&hs[idx] = b4;
    }
    __syncthreads();

    const int lane = t & 63, wm = t >> 6;
    const int ln = lane & 15;        // A row low / B col low / D col
    const int kk = lane >> 4;        // k-group (0..3)
    const int rowl = wm * 16 + ln;   // local A row

    f32x4 acc[16];
#pragma unroll
    for (int nf = 0; nf < 16; ++nf) acc[nf] = (f32x4){0.f, 0.f, 0.f, 0.f};

#pragma unroll
    for (int ks = 0; ks < 8; ++ks) {
        int aidx = (rowl * IN_DIM + ks * 32 + kk * 8) ^ ((rowl & 7) << 3);
        s8b a = *(const s8b*)&hs[aidx];
#pragma unroll
        for (int nf = 0; nf < 16; ++nf) {
            s8b b = *(const s8b*)&wt[(nf * 16 + ln) * IN_DIM + ks * 32 + kk * 8];
            acc[nf] = __builtin_amdgcn_mfma_f32_16x16x32_bf16(a, b, acc[nf], 0, 0, 0);
        }
    }

    // D layout: col = lane&15, row = (lane>>4)*4 + reg
#pragma unroll
    for (int nf = 0; nf < 16; ++nf) {
        int col = nf * 16 + ln;
        const bool isE = col < C_DIM;
        float rb = isE ? 0.f : resb[col - C_DIM];
#pragma unroll
        for (int r = 0; r < 4; ++r) {
            int nd = n0 + wm * 16 + kk * 4 + r;
            if (nd < N_NODES) {
                if (isE) emb[(size_t)nd * C_DIM + col] = acc[nf][r];
                else     out[(size_t)nd * C_DIM + (col - C_DIM)] = acc[nf][r] + rb;
            }
        }
    }

    // hl/hr: head hh covers cols hh*32..hh*32+31 = frags 2hh, 2hh+1
#pragma unroll
    for (int hh = 0; hh < HEADS; ++hh) {
        float al0 = a_l[hh * 32 + ln], al1 = a_l[hh * 32 + 16 + ln];
        float ar0 = a_r[hh * 32 + ln], ar1 = a_r[hh * 32 + 16 + ln];
#pragma unroll
        for (int r = 0; r < 4; ++r) {
            float pl = al0 * acc[2 * hh][r] + al1 * acc[2 * hh + 1][r];
            float pr = ar0 * acc[2 * hh][r] + ar1 * acc[2 * hh + 1][r];
#pragma unroll
            for (int m = 8; m >= 1; m >>= 1) {
                pl += __shfl_xor(pl, m);
                pr += __shfl_xor(pr, m);
            }
            int nd = n0 + wm * 16 + kk * 4 + r;
            if (ln == 0 && nd < N_NODES) {
                hl[nd * HEADS + hh] = pl;
                hr[nd * HEADS + hh] = pr;
            }
        }
    }
}

// ---------------------------------------------------------------------------
// histogram of destination degrees
__global__ void b1_hist(const int* __restrict__ col, unsigned int* __restrict__ counts) {
    int e = blockIdx.x * blockDim.x + threadIdx.x;
    if (e < N_EDGES) atomicAdd(&counts[col[e]], 1u);
}

// two-level exclusive scan
__global__ __launch_bounds__(256) void bscan1(const unsigned int* __restrict__ counts,
                                              unsigned int* __restrict__ offs,
                                              unsigned int* __restrict__ bsum) {
    __shared__ unsigned int s[256];
    int t = threadIdx.x;
    int g = blockIdx.x * 256 + t;
    unsigned int v = (g < N_NODES) ? counts[g] : 0u;
    s[t] = v;
    __syncthreads();
    for (int off = 1; off < 256; off <<= 1) {
        unsigned int x = (t >= off) ? s[t - off] : 0u;
        __syncthreads();
        s[t] += x;
        __syncthreads();
    }
    if (g < N_NODES) offs[g] = s[t] - v;
    if (t == 255) bsum[blockIdx.x] = s[255];
}

__global__ __launch_bounds__(512) void bscan2(unsigned int* __restrict__ bsum) {
    __shared__ unsigned int s[512];
    int t = threadIdx.x;
    unsigned int v = (t < NBLK_SCAN) ? bsum[t] : 0u;
    s[t] = v;
    __syncthreads();
    for (int off = 1; off < 512; off <<= 1) {
        unsigned int x = (t >= off) ? s[t - off] : 0u;
        __syncthreads();
        s[t] += x;
        __syncthreads();
    }
    if (t < NBLK_SCAN) bsum[t] = s[t] - v;
}

__global__ void bscan3(unsigned int* __restrict__ offs, const unsigned int* __restrict__ bsum,
                       unsigned int* __restrict__ cursor) {
    int g = blockIdx.x * blockDim.x + threadIdx.x;
    if (g < N_NODES) {
        unsigned int o = offs[g] + bsum[g >> 8];
        offs[g] = o;
        cursor[g] = o;
    }
    if (g == 0) offs[N_NODES] = N_EDGES;
}

// ---------------------------------------------------------------------------
// scatter: place each edge in its destination bucket; precompute leaky logit
__global__ void b4_scatter(const int* __restrict__ row, const int* __restrict__ col,
                           const int* __restrict__ ety,
                           const float* __restrict__ hl, const float* __restrict__ hr,
                           const float* __restrict__ het,
                           unsigned int* __restrict__ cursor,
                           float4* __restrict__ plog, int* __restrict__ prow) {
    int e = blockIdx.x * blockDim.x + threadIdx.x;
    if (e >= N_EDGES) return;
    int r = row[e], c = col[e], ty = ety[e];
    unsigned int pos = atomicAdd(&cursor[c], 1u);
    float4 l  = *(const float4*)&hl[r * 4];
    float4 rr = *(const float4*)&hr[c * 4];
    float4 te = *(const float4*)&het[ty * 4];
    float a0 = l.x + rr.x + te.x;
    float a1 = l.y + rr.y + te.y;
    float a2 = l.z + rr.z + te.z;
    float a3 = l.w + rr.w + te.w;
    a0 = a0 > 0.f ? a0 : NEG_SLOPE * a0;
    a1 = a1 > 0.f ? a1 : NEG_SLOPE * a1;
    a2 = a2 > 0.f ? a2 : NEG_SLOPE * a2;
    a3 = a3 > 0.f ? a3 : NEG_SLOPE * a3;
    plog[pos] = make_float4(a0, a1, a2, a3);
    prow[pos] = r;
}

// ---------------------------------------------------------------------------
// fused per-node softmax + aggregation + residual + ELU. One wave per node.
__device__ __forceinline__ void online_upd(float& m, float& s, float l) {
    float nm = fmaxf(m, l);
    s = s * __expf(m - nm) + __expf(l - nm);
    m = nm;
}

__global__ __launch_bounds__(256) void k_fused(
    const unsigned int* __restrict__ offs, const float4* __restrict__ plog,
    const int* __restrict__ prow, const float* __restrict__ emb,
    float* __restrict__ out) {
    __shared__ float alds[4][16][4];
    __shared__ int   rlds[4][16];
    const int w    = threadIdx.x >> 6;
    const int lane = threadIdx.x & 63;
    const int c    = blockIdx.x * 4 + w;
    if (c >= N_NODES) return;

    const unsigned int start = offs[c], end = offs[c + 1];

    float m0 = -1e30f, m1 = -1e30f, m2 = -1e30f, m3 = -1e30f;
    float s0 = 0.f, s1 = 0.f, s2 = 0.f, s3 = 0.f;
    for (unsigned int i = start + lane; i < end; i += 64) {
        float4 L = plog[i];
        online_upd(m0, s0, L.x);
        online_upd(m1, s1, L.y);
        online_upd(m2, s2, L.z);
        online_upd(m3, s3, L.w);
    }
#pragma unroll
    for (int off = 32; off >= 1; off >>= 1) {
        float mo, so, nm;
        mo = __shfl_xor(m0, off); so = __shfl_xor(s0, off);
        nm = fmaxf(m0, mo); s0 = s0 * __expf(m0 - nm) + so * __expf(mo - nm); m0 = nm;
        mo = __shfl_xor(m1, off); so = __shfl_xor(s1, off);
        nm = fmaxf(m1, mo); s1 = s1 * __expf(m1 - nm) + so * __expf(mo - nm); m1 = nm;
        mo = __shfl_xor(m2, off); so = __shfl_xor(s2, off);
        nm = fmaxf(m2, mo); s2 = s2 * __expf(m2 - nm) + so * __expf(mo - nm); m2 = nm;
        mo = __shfl_xor(m3, off); so = __shfl_xor(s3, off);
        nm = fmaxf(m3, mo); s3 = s3 * __expf(m3 - nm) + so * __expf(mo - nm); m3 = nm;
    }
    const bool hasE = end > start;
    const float i0 = hasE ? 1.f / s0 : 0.f;
    const float i1 = hasE ? 1.f / s1 : 0.f;
    const float i2 = hasE ? 1.f / s2 : 0.f;
    const float i3 = hasE ? 1.f / s3 : 0.f;

    const int h0 = lane >> 5;
    const int c0 = ((lane & 31) << 2) | h0;
    float acc0 = 0.f, acc1 = 0.f;

    for (unsigned int base = start; base < end; base += 16) {
        int cnt = (int)min(16u, end - base);
        if (lane < cnt) {
            float4 L = plog[base + lane];
            alds[w][lane][0] = __expf(L.x - m0) * i0;
            alds[w][lane][1] = __expf(L.y - m1) * i1;
            alds[w][lane][2] = __expf(L.z - m2) * i2;
            alds[w][lane][3] = __expf(L.w - m3) * i3;
            rlds[w][lane] = prow[base + lane];
        }
        for (int j = 0; j < cnt; ++j) {
            int r = rlds[w][j];
            float a0 = alds[w][j][h0];
            float a1 = alds[w][j][h0 + 2];
            const float* er = &emb[(size_t)r * C_DIM];
            acc0 = fmaf(a0, er[lane], acc0);
            acc1 = fmaf(a1, er[lane + 64], acc1);
        }
    }

    size_t ob = (size_t)c * C_DIM;
    float x0 = out[ob + c0] + acc0;
    float x1 = out[ob + c0 + 2] + acc1;
    out[ob + c0]     = x0 > 0.f ? x0 : expm1f(x0);
    out[ob + c0 + 2] = x1 > 0.f ? x1 : expm1f(x1);
}

// ---------------------------------------------------------------------------
extern "C" void kernel_launch(void* const* d_in, const int* in_sizes, int n_in,
                              void* d_out, int out_size, void* d_ws, size_t ws_size,
                              hipStream_t stream) {
    const float* h        = (const float*)d_in[0];
    const float* W        = (const float*)d_in[1];
    const float* edge_emb = (const float*)d_in[2];
    const float* Wr       = (const float*)d_in[3];
    const float* a_l      = (const float*)d_in[4];
    const float* a_r      = (const float*)d_in[5];
    const float* a_e      = (const float*)d_in[6];
    const float* res_W    = (const float*)d_in[7];
    const float* res_b    = (const float*)d_in[8];
    const int*   row      = (const int*)d_in[9];
    const int*   col      = (const int*)d_in[10];
    const int*   etype    = (const int*)d_in[11];
    float* out = (float*)d_out;

    // workspace layout (4-byte units); plog first for 16B alignment
    float* ws = (float*)d_ws;
    float4*       ws_plog  = (float4*)ws;                                   // E*4 floats
    float*        ws_emb   = ws + (size_t)N_EDGES * 4;                      // N*128
    float*        ws_hl    = ws_emb + (size_t)N_NODES * C_DIM;              // N*4
    float*        ws_hr    = ws_hl + (size_t)N_NODES * HEADS;               // N*4
    float*        ws_het   = ws_hr + (size_t)N_NODES * HEADS;               // 32
    unsigned int* ws_offs  = (unsigned int*)(ws_het + 32);                  // N+1
    unsigned int* ws_cur   = ws_offs + (N_NODES + 1);                       // N
    unsigned int* ws_cnt   = ws_cur + N_NODES;                              // N
    unsigned int* ws_bsum  = ws_cnt + N_NODES;                              // NBLK_SCAN
    int*          ws_prow  = (int*)(ws_bsum + NBLK_SCAN);                   // E
    short*        ws_wt    = (short*)(ws_prow + N_EDGES);                   // 256*256 bf16

    kz_init<<<(N_NODES + 255) / 256, 256, 0, stream>>>(ws_cnt, edge_emb, Wr, a_e, ws_het);

    kw_prep<<<256, 256, 0, stream>>>(W, res_W, ws_wt);

    k1_mfma<<<(N_NODES + 63) / 64, 256, 0, stream>>>(
        h, ws_wt, res_b, a_l, a_r, ws_emb, ws_hl, ws_hr, out);

    b1_hist<<<(N_EDGES + 255) / 256, 256, 0, stream>>>(col, ws_cnt);

    bscan1<<<NBLK_SCAN, 256, 0, stream>>>(ws_cnt, ws_offs, ws_bsum);
    bscan2<<<1, 512, 0, stream>>>(ws_bsum);
    bscan3<<<(N_NODES + 255) / 256, 256, 0, stream>>>(ws_offs, ws_bsum, ws_cur);

    b4_scatter<<<(N_EDGES + 255) / 256, 256, 0, stream>>>(
        row, col, etype, ws_hl, ws_hr, ws_het, ws_cur, ws_plog, ws_prow);

    k_fused<<<(N_NODES + 3) / 4, 256, 0, stream>>>(
        ws_offs, ws_plog, ws_prow, ws_emb, out);
}

// Round 4
// 707.155 us; speedup vs baseline: 5.4185x; 1.0960x over previous
//
#include <hip/hip_runtime.h>
#include <math.h>

#define N_NODES   100000
#define N_EDGES   1600000
#define IN_DIM    256
#define OUT_DIM   32
#define HEADS     4
#define C_DIM     128      // OUT_DIM*HEADS
#define EDGE_DIM  64
#define NUM_ETY   8
#define NEG_SLOPE 0.2f
#define NBLK_SCAN 391      // ceil(N_NODES/256)
#define M_TILE    128
#define BSTRIDE   40       // B LDS row stride in shorts (padded: 2-way conflicts only)

typedef __attribute__((ext_vector_type(8))) short s8b;   // 8 bf16 (4 VGPRs)
typedef __attribute__((ext_vector_type(4))) float f32x4; // MFMA accumulator

__device__ __forceinline__ short bf16rne(float x) {
    unsigned int u = __float_as_uint(x);
    unsigned int r = (u + 0x7FFFu + ((u >> 16) & 1u)) >> 16;
    return (short)r;
}

// ---------------------------------------------------------------------------
// kz: zero the degree counters; block 0 also computes h_e_type[8][4]
__global__ void kz_init(unsigned int* __restrict__ counts,
                        const float* __restrict__ edge_emb, const float* __restrict__ Wr,
                        const float* __restrict__ a_e, float* __restrict__ h_et) {
    int i = blockIdx.x * blockDim.x + threadIdx.x;
    if (i < N_NODES) counts[i] = 0u;
    if (blockIdx.x == 0 && threadIdx.x < NUM_ETY * HEADS) {
        int t = threadIdx.x / HEADS, hh = threadIdx.x % HEADS;
        float acc = 0.f;
        for (int f = 0; f < EDGE_DIM; ++f) {
            float et = 0.f;
            for (int e = 0; e < EDGE_DIM; ++e)
                et += edge_emb[t * EDGE_DIM + e] *
                      Wr[(t * EDGE_DIM + e) * (HEADS * EDGE_DIM) + hh * EDGE_DIM + f];
            acc += a_e[hh * EDGE_DIM + f] * et;
        }
        h_et[t * HEADS + hh] = acc;
    }
}

// kw: transpose+convert [W | resW] (fp32, [k][c]) -> Wt bf16 [c][k]
__global__ void kw_prep(const float* __restrict__ W, const float* __restrict__ resW,
                        short* __restrict__ wt) {
    int idx = blockIdx.x * 256 + threadIdx.x;     // 65536 = 256k x 256c
    int k = idx >> 8, c = idx & 255;
    float v = (c < C_DIM) ? W[k * C_DIM + c] : resW[k * C_DIM + (c - C_DIM)];
    wt[c * IN_DIM + k] = bf16rne(v);
}

// ---------------------------------------------------------------------------
// K1 (MFMA v2): block = 512 thr (8 waves, 4M x 2N), tile M=128 x N=256, K=256.
// A (h tile, bf16, swizzled) staged once; B (Wt) double-buffered per 32-k chunk.
__global__ __launch_bounds__(512, 2) void k1_mfma(
    const float* __restrict__ h, const short* __restrict__ wt,
    const float* __restrict__ resb,
    const float* __restrict__ a_l, const float* __restrict__ a_r,
    float* __restrict__ emb, float* __restrict__ hl, float* __restrict__ hr,
    float* __restrict__ out) {
    __shared__ short hs[M_TILE * IN_DIM];          // 64 KB
    __shared__ short bs[2][256 * BSTRIDE];         // 2 x 20 KB
    const int t  = threadIdx.x;
    const int n0 = blockIdx.x * M_TILE;

    // --- stage A: h[n0..n0+127][0..255] -> bf16 LDS, XOR swizzle per row
#pragma unroll
    for (int i = 0; i < 16; ++i) {
        int f4 = i * 512 + t;              // float4 index; 8192 total
        int row = f4 >> 6, q = f4 & 63;
        int rg = n0 + row;
        float4 v = make_float4(0.f, 0.f, 0.f, 0.f);
        if (rg < N_NODES) v = *(const float4*)&h[(size_t)rg * IN_DIM + q * 4];
        short4 b4;
        b4.x = bf16rne(v.x); b4.y = bf16rne(v.y);
        b4.z = bf16rne(v.z); b4.w = bf16rne(v.w);
        int idx = (row * IN_DIM + q * 4) ^ ((row & 7) << 3);
        *(short4*)&hs[idx] = b4;
    }

    // --- stage B chunk 0 (cols 0..255 x k 0..31)
    {
        int c = t >> 1, hf = t & 1;
        const s8b* src = (const s8b*)&wt[c * IN_DIM + hf * 16];
        s8b v0 = src[0], v1 = src[1];
        *(s8b*)&bs[0][c * BSTRIDE + hf * 16] = v0;
        *(s8b*)&bs[0][c * BSTRIDE + hf * 16 + 8] = v1;
    }
    __syncthreads();

    const int lane = t & 63, w = t >> 6;
    const int wm = w >> 1;           // 0..3 -> rows wm*32..+31
    const int wn = w & 1;            // 0..1 -> cols wn*128..+127
    const int ln = lane & 15;        // A row low / B col low / D col
    const int kk = lane >> 4;        // k-group (0..3)
    const int cstage = t >> 1, hstage = t & 1;

    f32x4 acc[2][8];
#pragma unroll
    for (int mf = 0; mf < 2; ++mf)
#pragma unroll
        for (int nf = 0; nf < 8; ++nf) acc[mf][nf] = (f32x4){0.f, 0.f, 0.f, 0.f};

    int cur = 0;
#pragma unroll
    for (int ks = 0; ks < 8; ++ks) {
        // issue next B-chunk global loads early (latency hides under MFMAs)
        s8b nb0 = {}, nb1 = {};
        if (ks < 7) {
            const s8b* src = (const s8b*)&wt[cstage * IN_DIM + (ks + 1) * 32 + hstage * 16];
            nb0 = src[0];
            nb1 = src[1];
        }

        // A fragments (2 m-frags)
        int r0 = wm * 32 + ln;
        int r1 = wm * 32 + 16 + ln;
        int a0i = (r0 * IN_DIM + ks * 32 + kk * 8) ^ ((r0 & 7) << 3);
        int a1i = (r1 * IN_DIM + ks * 32 + kk * 8) ^ ((r1 & 7) << 3);
        s8b a0 = *(const s8b*)&hs[a0i];
        s8b a1 = *(const s8b*)&hs[a1i];

        // B fragments (8 n-frags) + MFMAs
#pragma unroll
        for (int nf = 0; nf < 8; ++nf) {
            int c = wn * 128 + nf * 16 + ln;
            s8b b = *(const s8b*)&bs[cur][c * BSTRIDE + kk * 8];
            acc[0][nf] = __builtin_amdgcn_mfma_f32_16x16x32_bf16(a0, b, acc[0][nf], 0, 0, 0);
            acc[1][nf] = __builtin_amdgcn_mfma_f32_16x16x32_bf16(a1, b, acc[1][nf], 0, 0, 0);
        }

        if (ks < 7) {
            *(s8b*)&bs[cur ^ 1][cstage * BSTRIDE + hstage * 16] = nb0;
            *(s8b*)&bs[cur ^ 1][cstage * BSTRIDE + hstage * 16 + 8] = nb1;
        }
        __syncthreads();
        cur ^= 1;
    }

    // --- epilogue. D layout: col = ln, row = kk*4 + reg
    if (wn == 0) {
        // cols 0..127 -> emb
#pragma unroll
        for (int mf = 0; mf < 2; ++mf)
#pragma unroll
            for (int nf = 0; nf < 8; ++nf) {
                int col = nf * 16 + ln;
#pragma unroll
                for (int r = 0; r < 4; ++r) {
                    int nd = n0 + wm * 32 + mf * 16 + kk * 4 + r;
                    if (nd < N_NODES) emb[(size_t)nd * C_DIM + col] = acc[mf][nf][r];
                }
            }
        // hl/hr: head hh = frags 2hh, 2hh+1
#pragma unroll
        for (int mf = 0; mf < 2; ++mf)
#pragma unroll
            for (int hh = 0; hh < HEADS; ++hh) {
                float al0 = a_l[hh * 32 + ln], al1 = a_l[hh * 32 + 16 + ln];
                float ar0 = a_r[hh * 32 + ln], ar1 = a_r[hh * 32 + 16 + ln];
#pragma unroll
                for (int r = 0; r < 4; ++r) {
                    float pl = al0 * acc[mf][2 * hh][r] + al1 * acc[mf][2 * hh + 1][r];
                    float pr = ar0 * acc[mf][2 * hh][r] + ar1 * acc[mf][2 * hh + 1][r];
#pragma unroll
                    for (int m = 8; m >= 1; m >>= 1) {
                        pl += __shfl_xor(pl, m);
                        pr += __shfl_xor(pr, m);
                    }
                    int nd = n0 + wm * 32 + mf * 16 + kk * 4 + r;
                    if (ln == 0 && nd < N_NODES) {
                        hl[nd * HEADS + hh] = pl;
                        hr[nd * HEADS + hh] = pr;
                    }
                }
            }
    } else {
        // cols 128..255 -> out = res + b
#pragma unroll
        for (int mf = 0; mf < 2; ++mf)
#pragma unroll
            for (int nf = 0; nf < 8; ++nf) {
                int col = nf * 16 + ln;          // out channel
                float rb = resb[col];
#pragma unroll
                for (int r = 0; r < 4; ++r) {
                    int nd = n0 + wm * 32 + mf * 16 + kk * 4 + r;
                    if (nd < N_NODES) out[(size_t)nd * C_DIM + col] = acc[mf][nf][r] + rb;
                }
            }
    }
}

// ---------------------------------------------------------------------------
// histogram of destination degrees
__global__ void b1_hist(const int* __restrict__ col, unsigned int* __restrict__ counts) {
    int e = blockIdx.x * blockDim.x + threadIdx.x;
    if (e < N_EDGES) atomicAdd(&counts[col[e]], 1u);
}

// two-level exclusive scan
__global__ __launch_bounds__(256) void bscan1(const unsigned int* __restrict__ counts,
                                              unsigned int* __restrict__ offs,
                                              unsigned int* __restrict__ bsum) {
    __shared__ unsigned int s[256];
    int t = threadIdx.x;
    int g = blockIdx.x * 256 + t;
    unsigned int v = (g < N_NODES) ? counts[g] : 0u;
    s[t] = v;
    __syncthreads();
    for (int off = 1; off < 256; off <<= 1) {
        unsigned int x = (t >= off) ? s[t - off] : 0u;
        __syncthreads();
        s[t] += x;
        __syncthreads();
    }
    if (g < N_NODES) offs[g] = s[t] - v;
    if (t == 255) bsum[blockIdx.x] = s[255];
}

__global__ __launch_bounds__(512) void bscan2(unsigned int* __restrict__ bsum) {
    __shared__ unsigned int s[512];
    int t = threadIdx.x;
    unsigned int v = (t < NBLK_SCAN) ? bsum[t] : 0u;
    s[t] = v;
    __syncthreads();
    for (int off = 1; off < 512; off <<= 1) {
        unsigned int x = (t >= off) ? s[t - off] : 0u;
        __syncthreads();
        s[t] += x;
        __syncthreads();
    }
    if (t < NBLK_SCAN) bsum[t] = s[t] - v;
}

__global__ void bscan3(unsigned int* __restrict__ offs, const unsigned int* __restrict__ bsum,
                       unsigned int* __restrict__ cursor) {
    int g = blockIdx.x * blockDim.x + threadIdx.x;
    if (g < N_NODES) {
        unsigned int o = offs[g] + bsum[g >> 8];
        offs[g] = o;
        cursor[g] = o;
    }
    if (g == 0) offs[N_NODES] = N_EDGES;
}

// ---------------------------------------------------------------------------
// scatter: place each edge in its destination bucket; precompute leaky logit
__global__ void b4_scatter(const int* __restrict__ row, const int* __restrict__ col,
                           const int* __restrict__ ety,
                           const float* __restrict__ hl, const float* __restrict__ hr,
                           const float* __restrict__ het,
                           unsigned int* __restrict__ cursor,
                           float4* __restrict__ plog, int* __restrict__ prow) {
    int e = blockIdx.x * blockDim.x + threadIdx.x;
    if (e >= N_EDGES) return;
    int r = row[e], c = col[e], ty = ety[e];
    unsigned int pos = atomicAdd(&cursor[c], 1u);
    float4 l  = *(const float4*)&hl[r * 4];
    float4 rr = *(const float4*)&hr[c * 4];
    float4 te = *(const float4*)&het[ty * 4];
    float a0 = l.x + rr.x + te.x;
    float a1 = l.y + rr.y + te.y;
    float a2 = l.z + rr.z + te.z;
    float a3 = l.w + rr.w + te.w;
    a0 = a0 > 0.f ? a0 : NEG_SLOPE * a0;
    a1 = a1 > 0.f ? a1 : NEG_SLOPE * a1;
    a2 = a2 > 0.f ? a2 : NEG_SLOPE * a2;
    a3 = a3 > 0.f ? a3 : NEG_SLOPE * a3;
    plog[pos] = make_float4(a0, a1, a2, a3);
    prow[pos] = r;
}

// ---------------------------------------------------------------------------
// fused per-node softmax + aggregation + residual + ELU. One wave per node.
__device__ __forceinline__ void online_upd(float& m, float& s, float l) {
    float nm = fmaxf(m, l);
    s = s * __expf(m - nm) + __expf(l - nm);
    m = nm;
}

__global__ __launch_bounds__(256) void k_fused(
    const unsigned int* __restrict__ offs, const float4* __restrict__ plog,
    const int* __restrict__ prow, const float* __restrict__ emb,
    float* __restrict__ out) {
    __shared__ float alds[4][16][4];
    __shared__ int   rlds[4][16];
    const int w    = threadIdx.x >> 6;
    const int lane = threadIdx.x & 63;
    const int c    = blockIdx.x * 4 + w;
    if (c >= N_NODES) return;

    const unsigned int start = offs[c], end = offs[c + 1];

    float m0 = -1e30f, m1 = -1e30f, m2 = -1e30f, m3 = -1e30f;
    float s0 = 0.f, s1 = 0.f, s2 = 0.f, s3 = 0.f;
    for (unsigned int i = start + lane; i < end; i += 64) {
        float4 L = plog[i];
        online_upd(m0, s0, L.x);
        online_upd(m1, s1, L.y);
        online_upd(m2, s2, L.z);
        online_upd(m3, s3, L.w);
    }
#pragma unroll
    for (int off = 32; off >= 1; off >>= 1) {
        float mo, so, nm;
        mo = __shfl_xor(m0, off); so = __shfl_xor(s0, off);
        nm = fmaxf(m0, mo); s0 = s0 * __expf(m0 - nm) + so * __expf(mo - nm); m0 = nm;
        mo = __shfl_xor(m1, off); so = __shfl_xor(s1, off);
        nm = fmaxf(m1, mo); s1 = s1 * __expf(m1 - nm) + so * __expf(mo - nm); m1 = nm;
        mo = __shfl_xor(m2, off); so = __shfl_xor(s2, off);
        nm = fmaxf(m2, mo); s2 = s2 * __expf(m2 - nm) + so * __expf(mo - nm); m2 = nm;
        mo = __shfl_xor(m3, off); so = __shfl_xor(s3, off);
        nm = fmaxf(m3, mo); s3 = s3 * __expf(m3 - nm) + so * __expf(mo - nm); m3 = nm;
    }
    const bool hasE = end > start;
    const float i0 = hasE ? 1.f / s0 : 0.f;
    const float i1 = hasE ? 1.f / s1 : 0.f;
    const float i2 = hasE ? 1.f / s2 : 0.f;
    const float i3 = hasE ? 1.f / s3 : 0.f;

    const int h0 = lane >> 5;
    const int c0 = ((lane & 31) << 2) | h0;
    float acc0 = 0.f, acc1 = 0.f;

    for (unsigned int base = start; base < end; base += 16) {
        int cnt = (int)min(16u, end - base);
        if (lane < cnt) {
            float4 L = plog[base + lane];
            alds[w][lane][0] = __expf(L.x - m0) * i0;
            alds[w][lane][1] = __expf(L.y - m1) * i1;
            alds[w][lane][2] = __expf(L.z - m2) * i2;
            alds[w][lane][3] = __expf(L.w - m3) * i3;
            rlds[w][lane] = prow[base + lane];
        }
        for (int j = 0; j < cnt; ++j) {
            int r = rlds[w][j];
            float a0 = alds[w][j][h0];
            float a1 = alds[w][j][h0 + 2];
            const float* er = &emb[(size_t)r * C_DIM];
            acc0 = fmaf(a0, er[lane], acc0);
            acc1 = fmaf(a1, er[lane + 64], acc1);
        }
    }

    size_t ob = (size_t)c * C_DIM;
    float x0 = out[ob + c0] + acc0;
    float x1 = out[ob + c0 + 2] + acc1;
    out[ob + c0]     = x0 > 0.f ? x0 : expm1f(x0);
    out[ob + c0 + 2] = x1 > 0.f ? x1 : expm1f(x1);
}

// ---------------------------------------------------------------------------
extern "C" void kernel_launch(void* const* d_in, const int* in_sizes, int n_in,
                              void* d_out, int out_size, void* d_ws, size_t ws_size,
                              hipStream_t stream) {
    const float* h        = (const float*)d_in[0];
    const float* W        = (const float*)d_in[1];
    const float* edge_emb = (const float*)d_in[2];
    const float* Wr       = (const float*)d_in[3];
    const float* a_l      = (const float*)d_in[4];
    const float* a_r      = (const float*)d_in[5];
    const float* a_e      = (const float*)d_in[6];
    const float* res_W    = (const float*)d_in[7];
    const float* res_b    = (const float*)d_in[8];
    const int*   row      = (const int*)d_in[9];
    const int*   col      = (const int*)d_in[10];
    const int*   etype    = (const int*)d_in[11];
    float* out = (float*)d_out;

    // workspace layout (4-byte units); plog first for 16B alignment
    float* ws = (float*)d_ws;
    float4*       ws_plog  = (float4*)ws;                                   // E*4 floats
    float*        ws_emb   = ws + (size_t)N_EDGES * 4;                      // N*128
    float*        ws_hl    = ws_emb + (size_t)N_NODES * C_DIM;              // N*4
    float*        ws_hr    = ws_hl + (size_t)N_NODES * HEADS;               // N*4
    float*        ws_het   = ws_hr + (size_t)N_NODES * HEADS;               // 32
    unsigned int* ws_offs  = (unsigned int*)(ws_het + 32);                  // N+1
    unsigned int* ws_cur   = ws_offs + (N_NODES + 1);                       // N
    unsigned int* ws_cnt   = ws_cur + N_NODES;                              // N
    unsigned int* ws_bsum  = ws_cnt + N_NODES;                              // NBLK_SCAN
    int*          ws_prow  = (int*)(ws_bsum + NBLK_SCAN);                   // E
    short*        ws_wt    = (short*)(ws_prow + N_EDGES);                   // 256*256 bf16

    kz_init<<<(N_NODES + 255) / 256, 256, 0, stream>>>(ws_cnt, edge_emb, Wr, a_e, ws_het);

    kw_prep<<<256, 256, 0, stream>>>(W, res_W, ws_wt);

    k1_mfma<<<(N_NODES + M_TILE - 1) / M_TILE, 512, 0, stream>>>(
        h, ws_wt, res_b, a_l, a_r, ws_emb, ws_hl, ws_hr, out);

    b1_hist<<<(N_EDGES + 255) / 256, 256, 0, stream>>>(col, ws_cnt);

    bscan1<<<NBLK_SCAN, 256, 0, stream>>>(ws_cnt, ws_offs, ws_bsum);
    bscan2<<<1, 512, 0, stream>>>(ws_bsum);
    bscan3<<<(N_NODES + 255) / 256, 256, 0, stream>>>(ws_offs, ws_bsum, ws_cur);

    b4_scatter<<<(N_EDGES + 255) / 256, 256, 0, stream>>>(
        row, col, etype, ws_hl, ws_hr, ws_het, ws_cur, ws_plog, ws_prow);

    k_fused<<<(N_NODES + 3) / 4, 256, 0, stream>>>(
        ws_offs, ws_plog, ws_prow, ws_emb, out);
}

// Round 5
// 569.576 us; speedup vs baseline: 6.7273x; 1.2415x over previous
//
#include <hip/hip_runtime.h>
#include <math.h>

#define N_NODES   100000
#define N_EDGES   1600000
#define IN_DIM    256
#define OUT_DIM   32
#define HEADS     4
#define C_DIM     128      // OUT_DIM*HEADS
#define EDGE_DIM  64
#define NUM_ETY   8
#define NEG_SLOPE 0.2f
#define NBLK_SCAN 391      // ceil(N_NODES/256)
#define M_TILE    128
#define BSTRIDE   40       // B LDS row stride in shorts (padded: 2-way conflicts only)

typedef __attribute__((ext_vector_type(8))) short s8b;   // 8 bf16 (4 VGPRs)
typedef __attribute__((ext_vector_type(4))) float f32x4; // MFMA accumulator

__device__ __forceinline__ short bf16rne(float x) {
    unsigned int u = __float_as_uint(x);
    unsigned int r = (u + 0x7FFFu + ((u >> 16) & 1u)) >> 16;
    return (short)r;
}

// ---------------------------------------------------------------------------
// kz: zero the degree counters (pure memset now)
__global__ void kz_init(unsigned int* __restrict__ counts) {
    int i = blockIdx.x * blockDim.x + threadIdx.x;
    if (i < N_NODES) counts[i] = 0u;
}

// k_het: h_e_type[ty][hh] = sum_f a_e[hh][f] * sum_e edge_emb[ty][e]*Wr[ty][e][hh*64+f]
// grid: 8 blocks (one per type) x 256 thr (hh = t>>6, f = t&63)
__global__ __launch_bounds__(256) void k_het(
    const float* __restrict__ edge_emb, const float* __restrict__ Wr,
    const float* __restrict__ a_e, float* __restrict__ h_et) {
    __shared__ float ee[EDGE_DIM];
    const int t = threadIdx.x;
    const int ty = blockIdx.x;
    if (t < EDGE_DIM) ee[t] = edge_emb[ty * EDGE_DIM + t];
    __syncthreads();
    const int hh = t >> 6, f = t & 63;
    float acc = 0.f;
#pragma unroll 8
    for (int e = 0; e < EDGE_DIM; ++e)
        acc += ee[e] * Wr[(size_t)(ty * EDGE_DIM + e) * (HEADS * EDGE_DIM) + hh * EDGE_DIM + f];
    acc *= a_e[hh * EDGE_DIM + f];
#pragma unroll
    for (int m = 32; m >= 1; m >>= 1) acc += __shfl_xor(acc, m);
    if (f == 0) h_et[ty * HEADS + hh] = acc;
}

// kw: transpose+convert [W | resW] (fp32, [k][c]) -> Wt bf16 [c][k]
__global__ void kw_prep(const float* __restrict__ W, const float* __restrict__ resW,
                        short* __restrict__ wt) {
    int idx = blockIdx.x * 256 + threadIdx.x;     // 65536 = 256k x 256c
    int k = idx >> 8, c = idx & 255;
    float v = (c < C_DIM) ? W[k * C_DIM + c] : resW[k * C_DIM + (c - C_DIM)];
    wt[c * IN_DIM + k] = bf16rne(v);
}

// ---------------------------------------------------------------------------
// K1 (MFMA v2): block = 512 thr (8 waves, 4M x 2N), tile M=128 x N=256, K=256.
// A (h tile, bf16, swizzled) staged once; B (Wt) double-buffered per 32-k chunk.
__global__ __launch_bounds__(512, 2) void k1_mfma(
    const float* __restrict__ h, const short* __restrict__ wt,
    const float* __restrict__ resb,
    const float* __restrict__ a_l, const float* __restrict__ a_r,
    float* __restrict__ emb, float* __restrict__ hl, float* __restrict__ hr,
    float* __restrict__ out) {
    __shared__ short hs[M_TILE * IN_DIM];          // 64 KB
    __shared__ short bs[2][256 * BSTRIDE];         // 2 x 20 KB
    const int t  = threadIdx.x;
    const int n0 = blockIdx.x * M_TILE;

    // --- stage A: h[n0..n0+127][0..255] -> bf16 LDS, XOR swizzle per row
#pragma unroll
    for (int i = 0; i < 16; ++i) {
        int f4 = i * 512 + t;              // float4 index; 8192 total
        int row = f4 >> 6, q = f4 & 63;
        int rg = n0 + row;
        float4 v = make_float4(0.f, 0.f, 0.f, 0.f);
        if (rg < N_NODES) v = *(const float4*)&h[(size_t)rg * IN_DIM + q * 4];
        short4 b4;
        b4.x = bf16rne(v.x); b4.y = bf16rne(v.y);
        b4.z = bf16rne(v.z); b4.w = bf16rne(v.w);
        int idx = (row * IN_DIM + q * 4) ^ ((row & 7) << 3);
        *(short4*)&hs[idx] = b4;
    }

    // --- stage B chunk 0 (cols 0..255 x k 0..31)
    {
        int c = t >> 1, hf = t & 1;
        const s8b* src = (const s8b*)&wt[c * IN_DIM + hf * 16];
        s8b v0 = src[0], v1 = src[1];
        *(s8b*)&bs[0][c * BSTRIDE + hf * 16] = v0;
        *(s8b*)&bs[0][c * BSTRIDE + hf * 16 + 8] = v1;
    }
    __syncthreads();

    const int lane = t & 63, w = t >> 6;
    const int wm = w >> 1;           // 0..3 -> rows wm*32..+31
    const int wn = w & 1;            // 0..1 -> cols wn*128..+127
    const int ln = lane & 15;        // A row low / B col low / D col
    const int kk = lane >> 4;        // k-group (0..3)
    const int cstage = t >> 1, hstage = t & 1;

    f32x4 acc[2][8];
#pragma unroll
    for (int mf = 0; mf < 2; ++mf)
#pragma unroll
        for (int nf = 0; nf < 8; ++nf) acc[mf][nf] = (f32x4){0.f, 0.f, 0.f, 0.f};

    int cur = 0;
#pragma unroll
    for (int ks = 0; ks < 8; ++ks) {
        // issue next B-chunk global loads early (latency hides under MFMAs)
        s8b nb0 = {}, nb1 = {};
        if (ks < 7) {
            const s8b* src = (const s8b*)&wt[cstage * IN_DIM + (ks + 1) * 32 + hstage * 16];
            nb0 = src[0];
            nb1 = src[1];
        }

        // A fragments (2 m-frags)
        int r0 = wm * 32 + ln;
        int r1 = wm * 32 + 16 + ln;
        int a0i = (r0 * IN_DIM + ks * 32 + kk * 8) ^ ((r0 & 7) << 3);
        int a1i = (r1 * IN_DIM + ks * 32 + kk * 8) ^ ((r1 & 7) << 3);
        s8b a0 = *(const s8b*)&hs[a0i];
        s8b a1 = *(const s8b*)&hs[a1i];

        // B fragments (8 n-frags) + MFMAs
#pragma unroll
        for (int nf = 0; nf < 8; ++nf) {
            int c = wn * 128 + nf * 16 + ln;
            s8b b = *(const s8b*)&bs[cur][c * BSTRIDE + kk * 8];
            acc[0][nf] = __builtin_amdgcn_mfma_f32_16x16x32_bf16(a0, b, acc[0][nf], 0, 0, 0);
            acc[1][nf] = __builtin_amdgcn_mfma_f32_16x16x32_bf16(a1, b, acc[1][nf], 0, 0, 0);
        }

        if (ks < 7) {
            *(s8b*)&bs[cur ^ 1][cstage * BSTRIDE + hstage * 16] = nb0;
            *(s8b*)&bs[cur ^ 1][cstage * BSTRIDE + hstage * 16 + 8] = nb1;
        }
        __syncthreads();
        cur ^= 1;
    }

    // --- epilogue. D layout: col = ln, row = kk*4 + reg
    if (wn == 0) {
        // cols 0..127 -> emb
#pragma unroll
        for (int mf = 0; mf < 2; ++mf)
#pragma unroll
            for (int nf = 0; nf < 8; ++nf) {
                int col = nf * 16 + ln;
#pragma unroll
                for (int r = 0; r < 4; ++r) {
                    int nd = n0 + wm * 32 + mf * 16 + kk * 4 + r;
                    if (nd < N_NODES) emb[(size_t)nd * C_DIM + col] = acc[mf][nf][r];
                }
            }
        // hl/hr: head hh = frags 2hh, 2hh+1
#pragma unroll
        for (int mf = 0; mf < 2; ++mf)
#pragma unroll
            for (int hh = 0; hh < HEADS; ++hh) {
                float al0 = a_l[hh * 32 + ln], al1 = a_l[hh * 32 + 16 + ln];
                float ar0 = a_r[hh * 32 + ln], ar1 = a_r[hh * 32 + 16 + ln];
#pragma unroll
                for (int r = 0; r < 4; ++r) {
                    float pl = al0 * acc[mf][2 * hh][r] + al1 * acc[mf][2 * hh + 1][r];
                    float pr = ar0 * acc[mf][2 * hh][r] + ar1 * acc[mf][2 * hh + 1][r];
#pragma unroll
                    for (int m = 8; m >= 1; m >>= 1) {
                        pl += __shfl_xor(pl, m);
                        pr += __shfl_xor(pr, m);
                    }
                    int nd = n0 + wm * 32 + mf * 16 + kk * 4 + r;
                    if (ln == 0 && nd < N_NODES) {
                        hl[nd * HEADS + hh] = pl;
                        hr[nd * HEADS + hh] = pr;
                    }
                }
            }
    } else {
        // cols 128..255 -> out = res + b
#pragma unroll
        for (int mf = 0; mf < 2; ++mf)
#pragma unroll
            for (int nf = 0; nf < 8; ++nf) {
                int col = nf * 16 + ln;          // out channel
                float rb = resb[col];
#pragma unroll
                for (int r = 0; r < 4; ++r) {
                    int nd = n0 + wm * 32 + mf * 16 + kk * 4 + r;
                    if (nd < N_NODES) out[(size_t)nd * C_DIM + col] = acc[mf][nf][r] + rb;
                }
            }
    }
}

// ---------------------------------------------------------------------------
// histogram of destination degrees
__global__ void b1_hist(const int* __restrict__ col, unsigned int* __restrict__ counts) {
    int e = blockIdx.x * blockDim.x + threadIdx.x;
    if (e < N_EDGES) atomicAdd(&counts[col[e]], 1u);
}

// two-level exclusive scan
__global__ __launch_bounds__(256) void bscan1(const unsigned int* __restrict__ counts,
                                              unsigned int* __restrict__ offs,
                                              unsigned int* __restrict__ bsum) {
    __shared__ unsigned int s[256];
    int t = threadIdx.x;
    int g = blockIdx.x * 256 + t;
    unsigned int v = (g < N_NODES) ? counts[g] : 0u;
    s[t] = v;
    __syncthreads();
    for (int off = 1; off < 256; off <<= 1) {
        unsigned int x = (t >= off) ? s[t - off] : 0u;
        __syncthreads();
        s[t] += x;
        __syncthreads();
    }
    if (g < N_NODES) offs[g] = s[t] - v;
    if (t == 255) bsum[blockIdx.x] = s[255];
}

__global__ __launch_bounds__(512) void bscan2(unsigned int* __restrict__ bsum) {
    __shared__ unsigned int s[512];
    int t = threadIdx.x;
    unsigned int v = (t < NBLK_SCAN) ? bsum[t] : 0u;
    s[t] = v;
    __syncthreads();
    for (int off = 1; off < 512; off <<= 1) {
        unsigned int x = (t >= off) ? s[t - off] : 0u;
        __syncthreads();
        s[t] += x;
        __syncthreads();
    }
    if (t < NBLK_SCAN) bsum[t] = s[t] - v;
}

__global__ void bscan3(unsigned int* __restrict__ offs, const unsigned int* __restrict__ bsum,
                       unsigned int* __restrict__ cursor) {
    int g = blockIdx.x * blockDim.x + threadIdx.x;
    if (g < N_NODES) {
        unsigned int o = offs[g] + bsum[g >> 8];
        offs[g] = o;
        cursor[g] = o;
    }
    if (g == 0) offs[N_NODES] = N_EDGES;
}

// ---------------------------------------------------------------------------
// scatter: place each edge in its destination bucket; precompute leaky logit
__global__ void b4_scatter(const int* __restrict__ row, const int* __restrict__ col,
                           const int* __restrict__ ety,
                           const float* __restrict__ hl, const float* __restrict__ hr,
                           const float* __restrict__ het,
                           unsigned int* __restrict__ cursor,
                           float4* __restrict__ plog, int* __restrict__ prow) {
    int e = blockIdx.x * blockDim.x + threadIdx.x;
    if (e >= N_EDGES) return;
    int r = row[e], c = col[e], ty = ety[e];
    unsigned int pos = atomicAdd(&cursor[c], 1u);
    float4 l  = *(const float4*)&hl[r * 4];
    float4 rr = *(const float4*)&hr[c * 4];
    float4 te = *(const float4*)&het[ty * 4];
    float a0 = l.x + rr.x + te.x;
    float a1 = l.y + rr.y + te.y;
    float a2 = l.z + rr.z + te.z;
    float a3 = l.w + rr.w + te.w;
    a0 = a0 > 0.f ? a0 : NEG_SLOPE * a0;
    a1 = a1 > 0.f ? a1 : NEG_SLOPE * a1;
    a2 = a2 > 0.f ? a2 : NEG_SLOPE * a2;
    a3 = a3 > 0.f ? a3 : NEG_SLOPE * a3;
    plog[pos] = make_float4(a0, a1, a2, a3);
    prow[pos] = r;
}

// ---------------------------------------------------------------------------
// fused per-node softmax + aggregation + residual + ELU. One wave per node.
__device__ __forceinline__ void online_upd(float& m, float& s, float l) {
    float nm = fmaxf(m, l);
    s = s * __expf(m - nm) + __expf(l - nm);
    m = nm;
}

__global__ __launch_bounds__(256) void k_fused(
    const unsigned int* __restrict__ offs, const float4* __restrict__ plog,
    const int* __restrict__ prow, const float* __restrict__ emb,
    float* __restrict__ out) {
    __shared__ float alds[4][16][4];
    __shared__ int   rlds[4][16];
    const int w    = threadIdx.x >> 6;
    const int lane = threadIdx.x & 63;
    const int c    = blockIdx.x * 4 + w;
    if (c >= N_NODES) return;

    const unsigned int start = offs[c], end = offs[c + 1];

    float m0 = -1e30f, m1 = -1e30f, m2 = -1e30f, m3 = -1e30f;
    float s0 = 0.f, s1 = 0.f, s2 = 0.f, s3 = 0.f;
    for (unsigned int i = start + lane; i < end; i += 64) {
        float4 L = plog[i];
        online_upd(m0, s0, L.x);
        online_upd(m1, s1, L.y);
        online_upd(m2, s2, L.z);
        online_upd(m3, s3, L.w);
    }
#pragma unroll
    for (int off = 32; off >= 1; off >>= 1) {
        float mo, so, nm;
        mo = __shfl_xor(m0, off); so = __shfl_xor(s0, off);
        nm = fmaxf(m0, mo); s0 = s0 * __expf(m0 - nm) + so * __expf(mo - nm); m0 = nm;
        mo = __shfl_xor(m1, off); so = __shfl_xor(s1, off);
        nm = fmaxf(m1, mo); s1 = s1 * __expf(m1 - nm) + so * __expf(mo - nm); m1 = nm;
        mo = __shfl_xor(m2, off); so = __shfl_xor(s2, off);
        nm = fmaxf(m2, mo); s2 = s2 * __expf(m2 - nm) + so * __expf(mo - nm); m2 = nm;
        mo = __shfl_xor(m3, off); so = __shfl_xor(s3, off);
        nm = fmaxf(m3, mo); s3 = s3 * __expf(m3 - nm) + so * __expf(mo - nm); m3 = nm;
    }
    const bool hasE = end > start;
    const float i0 = hasE ? 1.f / s0 : 0.f;
    const float i1 = hasE ? 1.f / s1 : 0.f;
    const float i2 = hasE ? 1.f / s2 : 0.f;
    const float i3 = hasE ? 1.f / s3 : 0.f;

    const int h0 = lane >> 5;
    const int c0 = ((lane & 31) << 2) | h0;
    float acc0 = 0.f, acc1 = 0.f;

    for (unsigned int base = start; base < end; base += 16) {
        int cnt = (int)min(16u, end - base);
        if (lane < cnt) {
            float4 L = plog[base + lane];
            alds[w][lane][0] = __expf(L.x - m0) * i0;
            alds[w][lane][1] = __expf(L.y - m1) * i1;
            alds[w][lane][2] = __expf(L.z - m2) * i2;
            alds[w][lane][3] = __expf(L.w - m3) * i3;
            rlds[w][lane] = prow[base + lane];
        }
        for (int j = 0; j < cnt; ++j) {
            int r = rlds[w][j];
            float a0 = alds[w][j][h0];
            float a1 = alds[w][j][h0 + 2];
            const float* er = &emb[(size_t)r * C_DIM];
            acc0 = fmaf(a0, er[lane], acc0);
            acc1 = fmaf(a1, er[lane + 64], acc1);
        }
    }

    size_t ob = (size_t)c * C_DIM;
    float x0 = out[ob + c0] + acc0;
    float x1 = out[ob + c0 + 2] + acc1;
    out[ob + c0]     = x0 > 0.f ? x0 : expm1f(x0);
    out[ob + c0 + 2] = x1 > 0.f ? x1 : expm1f(x1);
}

// ---------------------------------------------------------------------------
extern "C" void kernel_launch(void* const* d_in, const int* in_sizes, int n_in,
                              void* d_out, int out_size, void* d_ws, size_t ws_size,
                              hipStream_t stream) {
    const float* h        = (const float*)d_in[0];
    const float* W        = (const float*)d_in[1];
    const float* edge_emb = (const float*)d_in[2];
    const float* Wr       = (const float*)d_in[3];
    const float* a_l      = (const float*)d_in[4];
    const float* a_r      = (const float*)d_in[5];
    const float* a_e      = (const float*)d_in[6];
    const float* res_W    = (const float*)d_in[7];
    const float* res_b    = (const float*)d_in[8];
    const int*   row      = (const int*)d_in[9];
    const int*   col      = (const int*)d_in[10];
    const int*   etype    = (const int*)d_in[11];
    float* out = (float*)d_out;

    // workspace layout (4-byte units); plog first for 16B alignment
    float* ws = (float*)d_ws;
    float4*       ws_plog  = (float4*)ws;                                   // E*4 floats
    float*        ws_emb   = ws + (size_t)N_EDGES * 4;                      // N*128
    float*        ws_hl    = ws_emb + (size_t)N_NODES * C_DIM;              // N*4
    float*        ws_hr    = ws_hl + (size_t)N_NODES * HEADS;               // N*4
    float*        ws_het   = ws_hr + (size_t)N_NODES * HEADS;               // 32
    unsigned int* ws_offs  = (unsigned int*)(ws_het + 32);                  // N+1
    unsigned int* ws_cur   = ws_offs + (N_NODES + 1);                       // N
    unsigned int* ws_cnt   = ws_cur + N_NODES;                              // N
    unsigned int* ws_bsum  = ws_cnt + N_NODES;                              // NBLK_SCAN
    int*          ws_prow  = (int*)(ws_bsum + NBLK_SCAN);                   // E
    short*        ws_wt    = (short*)(ws_prow + N_EDGES);                   // 256*256 bf16

    kz_init<<<(N_NODES + 255) / 256, 256, 0, stream>>>(ws_cnt);

    k_het<<<NUM_ETY, 256, 0, stream>>>(edge_emb, Wr, a_e, ws_het);

    kw_prep<<<256, 256, 0, stream>>>(W, res_W, ws_wt);

    k1_mfma<<<(N_NODES + M_TILE - 1) / M_TILE, 512, 0, stream>>>(
        h, ws_wt, res_b, a_l, a_r, ws_emb, ws_hl, ws_hr, out);

    b1_hist<<<(N_EDGES + 255) / 256, 256, 0, stream>>>(col, ws_cnt);

    bscan1<<<NBLK_SCAN, 256, 0, stream>>>(ws_cnt, ws_offs, ws_bsum);
    bscan2<<<1, 512, 0, stream>>>(ws_bsum);
    bscan3<<<(N_NODES + 255) / 256, 256, 0, stream>>>(ws_offs, ws_bsum, ws_cur);

    b4_scatter<<<(N_EDGES + 255) / 256, 256, 0, stream>>>(
        row, col, etype, ws_hl, ws_hr, ws_het, ws_cur, ws_plog, ws_prow);

    k_fused<<<(N_NODES + 3) / 4, 256, 0, stream>>>(
        ws_offs, ws_plog, ws_prow, ws_emb, out);
}

// Round 6
// 551.504 us; speedup vs baseline: 6.9477x; 1.0328x over previous
//
#include <hip/hip_runtime.h>
#include <math.h>

#define N_NODES   100000
#define N_EDGES   1600000
#define IN_DIM    256
#define OUT_DIM   32
#define HEADS     4
#define C_DIM     128      // OUT_DIM*HEADS
#define EDGE_DIM  64
#define NUM_ETY   8
#define NEG_SLOPE 0.2f
#define NBLK_SCAN 391      // ceil(N_NODES/256)
#define M_TILE    128
#define BSTRIDE   40       // B LDS row stride in shorts (padded: 2-way conflicts only)

typedef __attribute__((ext_vector_type(8))) short s8b;   // 8 bf16 (4 VGPRs)
typedef __attribute__((ext_vector_type(4))) float f32x4; // MFMA accumulator
typedef unsigned short ushort_t;

__device__ __forceinline__ short bf16rne(float x) {
    unsigned int u = __float_as_uint(x);
    unsigned int r = (u + 0x7FFFu + ((u >> 16) & 1u)) >> 16;
    return (short)r;
}

// ---------------------------------------------------------------------------
// kz: zero the degree counters (pure memset now)
__global__ void kz_init(unsigned int* __restrict__ counts) {
    int i = blockIdx.x * blockDim.x + threadIdx.x;
    if (i < N_NODES) counts[i] = 0u;
}

// k_het: h_e_type[ty][hh] = sum_f a_e[hh][f] * sum_e edge_emb[ty][e]*Wr[ty][e][hh*64+f]
__global__ __launch_bounds__(256) void k_het(
    const float* __restrict__ edge_emb, const float* __restrict__ Wr,
    const float* __restrict__ a_e, float* __restrict__ h_et) {
    __shared__ float ee[EDGE_DIM];
    const int t = threadIdx.x;
    const int ty = blockIdx.x;
    if (t < EDGE_DIM) ee[t] = edge_emb[ty * EDGE_DIM + t];
    __syncthreads();
    const int hh = t >> 6, f = t & 63;
    float acc = 0.f;
#pragma unroll 8
    for (int e = 0; e < EDGE_DIM; ++e)
        acc += ee[e] * Wr[(size_t)(ty * EDGE_DIM + e) * (HEADS * EDGE_DIM) + hh * EDGE_DIM + f];
    acc *= a_e[hh * EDGE_DIM + f];
#pragma unroll
    for (int m = 32; m >= 1; m >>= 1) acc += __shfl_xor(acc, m);
    if (f == 0) h_et[ty * HEADS + hh] = acc;
}

// kw: transpose+convert [W | resW] (fp32, [k][c]) -> Wt bf16 [c][k]
__global__ void kw_prep(const float* __restrict__ W, const float* __restrict__ resW,
                        short* __restrict__ wt) {
    int idx = blockIdx.x * 256 + threadIdx.x;     // 65536 = 256k x 256c
    int k = idx >> 8, c = idx & 255;
    float v = (c < C_DIM) ? W[k * C_DIM + c] : resW[k * C_DIM + (c - C_DIM)];
    wt[c * IN_DIM + k] = bf16rne(v);
}

// ---------------------------------------------------------------------------
// K1 (MFMA v2): block = 512 thr (8 waves, 4M x 2N), tile M=128 x N=256, K=256.
// emb is stored as bf16 (only consumer is the k_fused gather).
__global__ __launch_bounds__(512, 2) void k1_mfma(
    const float* __restrict__ h, const short* __restrict__ wt,
    const float* __restrict__ resb,
    const float* __restrict__ a_l, const float* __restrict__ a_r,
    ushort_t* __restrict__ embh, float* __restrict__ hl, float* __restrict__ hr,
    float* __restrict__ out) {
    __shared__ short hs[M_TILE * IN_DIM];          // 64 KB
    __shared__ short bs[2][256 * BSTRIDE];         // 2 x 20 KB
    const int t  = threadIdx.x;
    const int n0 = blockIdx.x * M_TILE;

    // --- stage A: h[n0..n0+127][0..255] -> bf16 LDS, XOR swizzle per row
#pragma unroll
    for (int i = 0; i < 16; ++i) {
        int f4 = i * 512 + t;              // float4 index; 8192 total
        int row = f4 >> 6, q = f4 & 63;
        int rg = n0 + row;
        float4 v = make_float4(0.f, 0.f, 0.f, 0.f);
        if (rg < N_NODES) v = *(const float4*)&h[(size_t)rg * IN_DIM + q * 4];
        short4 b4;
        b4.x = bf16rne(v.x); b4.y = bf16rne(v.y);
        b4.z = bf16rne(v.z); b4.w = bf16rne(v.w);
        int idx = (row * IN_DIM + q * 4) ^ ((row & 7) << 3);
        *(short4*)&hs[idx] = b4;
    }

    // --- stage B chunk 0 (cols 0..255 x k 0..31)
    {
        int c = t >> 1, hf = t & 1;
        const s8b* src = (const s8b*)&wt[c * IN_DIM + hf * 16];
        s8b v0 = src[0], v1 = src[1];
        *(s8b*)&bs[0][c * BSTRIDE + hf * 16] = v0;
        *(s8b*)&bs[0][c * BSTRIDE + hf * 16 + 8] = v1;
    }
    __syncthreads();

    const int lane = t & 63, w = t >> 6;
    const int wm = w >> 1;           // 0..3 -> rows wm*32..+31
    const int wn = w & 1;            // 0..1 -> cols wn*128..+127
    const int ln = lane & 15;        // A row low / B col low / D col
    const int kk = lane >> 4;        // k-group (0..3)
    const int cstage = t >> 1, hstage = t & 1;

    f32x4 acc[2][8];
#pragma unroll
    for (int mf = 0; mf < 2; ++mf)
#pragma unroll
        for (int nf = 0; nf < 8; ++nf) acc[mf][nf] = (f32x4){0.f, 0.f, 0.f, 0.f};

    int cur = 0;
#pragma unroll
    for (int ks = 0; ks < 8; ++ks) {
        // issue next B-chunk global loads early (latency hides under MFMAs)
        s8b nb0 = {}, nb1 = {};
        if (ks < 7) {
            const s8b* src = (const s8b*)&wt[cstage * IN_DIM + (ks + 1) * 32 + hstage * 16];
            nb0 = src[0];
            nb1 = src[1];
        }

        // A fragments (2 m-frags)
        int r0 = wm * 32 + ln;
        int r1 = wm * 32 + 16 + ln;
        int a0i = (r0 * IN_DIM + ks * 32 + kk * 8) ^ ((r0 & 7) << 3);
        int a1i = (r1 * IN_DIM + ks * 32 + kk * 8) ^ ((r1 & 7) << 3);
        s8b a0 = *(const s8b*)&hs[a0i];
        s8b a1 = *(const s8b*)&hs[a1i];

        // B fragments (8 n-frags) + MFMAs
#pragma unroll
        for (int nf = 0; nf < 8; ++nf) {
            int c = wn * 128 + nf * 16 + ln;
            s8b b = *(const s8b*)&bs[cur][c * BSTRIDE + kk * 8];
            acc[0][nf] = __builtin_amdgcn_mfma_f32_16x16x32_bf16(a0, b, acc[0][nf], 0, 0, 0);
            acc[1][nf] = __builtin_amdgcn_mfma_f32_16x16x32_bf16(a1, b, acc[1][nf], 0, 0, 0);
        }

        if (ks < 7) {
            *(s8b*)&bs[cur ^ 1][cstage * BSTRIDE + hstage * 16] = nb0;
            *(s8b*)&bs[cur ^ 1][cstage * BSTRIDE + hstage * 16 + 8] = nb1;
        }
        __syncthreads();
        cur ^= 1;
    }

    // --- epilogue. D layout: col = ln, row = kk*4 + reg
    if (wn == 0) {
        // cols 0..127 -> emb (bf16)
#pragma unroll
        for (int mf = 0; mf < 2; ++mf)
#pragma unroll
            for (int nf = 0; nf < 8; ++nf) {
                int col = nf * 16 + ln;
#pragma unroll
                for (int r = 0; r < 4; ++r) {
                    int nd = n0 + wm * 32 + mf * 16 + kk * 4 + r;
                    if (nd < N_NODES)
                        embh[(size_t)nd * C_DIM + col] = (ushort_t)bf16rne(acc[mf][nf][r]);
                }
            }
        // hl/hr from fp32 accumulators: head hh = frags 2hh, 2hh+1
#pragma unroll
        for (int mf = 0; mf < 2; ++mf)
#pragma unroll
            for (int hh = 0; hh < HEADS; ++hh) {
                float al0 = a_l[hh * 32 + ln], al1 = a_l[hh * 32 + 16 + ln];
                float ar0 = a_r[hh * 32 + ln], ar1 = a_r[hh * 32 + 16 + ln];
#pragma unroll
                for (int r = 0; r < 4; ++r) {
                    float pl = al0 * acc[mf][2 * hh][r] + al1 * acc[mf][2 * hh + 1][r];
                    float pr = ar0 * acc[mf][2 * hh][r] + ar1 * acc[mf][2 * hh + 1][r];
#pragma unroll
                    for (int m = 8; m >= 1; m >>= 1) {
                        pl += __shfl_xor(pl, m);
                        pr += __shfl_xor(pr, m);
                    }
                    int nd = n0 + wm * 32 + mf * 16 + kk * 4 + r;
                    if (ln == 0 && nd < N_NODES) {
                        hl[nd * HEADS + hh] = pl;
                        hr[nd * HEADS + hh] = pr;
                    }
                }
            }
    } else {
        // cols 128..255 -> out = res + b
#pragma unroll
        for (int mf = 0; mf < 2; ++mf)
#pragma unroll
            for (int nf = 0; nf < 8; ++nf) {
                int col = nf * 16 + ln;          // out channel
                float rb = resb[col];
#pragma unroll
                for (int r = 0; r < 4; ++r) {
                    int nd = n0 + wm * 32 + mf * 16 + kk * 4 + r;
                    if (nd < N_NODES) out[(size_t)nd * C_DIM + col] = acc[mf][nf][r] + rb;
                }
            }
    }
}

// ---------------------------------------------------------------------------
// histogram of destination degrees
__global__ void b1_hist(const int* __restrict__ col, unsigned int* __restrict__ counts) {
    int e = blockIdx.x * blockDim.x + threadIdx.x;
    if (e < N_EDGES) atomicAdd(&counts[col[e]], 1u);
}

// two-level exclusive scan
__global__ __launch_bounds__(256) void bscan1(const unsigned int* __restrict__ counts,
                                              unsigned int* __restrict__ offs,
                                              unsigned int* __restrict__ bsum) {
    __shared__ unsigned int s[256];
    int t = threadIdx.x;
    int g = blockIdx.x * 256 + t;
    unsigned int v = (g < N_NODES) ? counts[g] : 0u;
    s[t] = v;
    __syncthreads();
    for (int off = 1; off < 256; off <<= 1) {
        unsigned int x = (t >= off) ? s[t - off] : 0u;
        __syncthreads();
        s[t] += x;
        __syncthreads();
    }
    if (g < N_NODES) offs[g] = s[t] - v;
    if (t == 255) bsum[blockIdx.x] = s[255];
}

__global__ __launch_bounds__(512) void bscan2(unsigned int* __restrict__ bsum) {
    __shared__ unsigned int s[512];
    int t = threadIdx.x;
    unsigned int v = (t < NBLK_SCAN) ? bsum[t] : 0u;
    s[t] = v;
    __syncthreads();
    for (int off = 1; off < 512; off <<= 1) {
        unsigned int x = (t >= off) ? s[t - off] : 0u;
        __syncthreads();
        s[t] += x;
        __syncthreads();
    }
    if (t < NBLK_SCAN) bsum[t] = s[t] - v;
}

__global__ void bscan3(unsigned int* __restrict__ offs, const unsigned int* __restrict__ bsum,
                       unsigned int* __restrict__ cursor) {
    int g = blockIdx.x * blockDim.x + threadIdx.x;
    if (g < N_NODES) {
        unsigned int o = offs[g] + bsum[g >> 8];
        offs[g] = o;
        cursor[g] = o;
    }
    if (g == 0) offs[N_NODES] = N_EDGES;
}

// ---------------------------------------------------------------------------
// scatter: place each edge in its destination bucket; precompute leaky logit
__global__ void b4_scatter(const int* __restrict__ row, const int* __restrict__ col,
                           const int* __restrict__ ety,
                           const float* __restrict__ hl, const float* __restrict__ hr,
                           const float* __restrict__ het,
                           unsigned int* __restrict__ cursor,
                           float4* __restrict__ plog, int* __restrict__ prow) {
    int e = blockIdx.x * blockDim.x + threadIdx.x;
    if (e >= N_EDGES) return;
    int r = row[e], c = col[e], ty = ety[e];
    unsigned int pos = atomicAdd(&cursor[c], 1u);
    float4 l  = *(const float4*)&hl[r * 4];
    float4 rr = *(const float4*)&hr[c * 4];
    float4 te = *(const float4*)&het[ty * 4];
    float a0 = l.x + rr.x + te.x;
    float a1 = l.y + rr.y + te.y;
    float a2 = l.z + rr.z + te.z;
    float a3 = l.w + rr.w + te.w;
    a0 = a0 > 0.f ? a0 : NEG_SLOPE * a0;
    a1 = a1 > 0.f ? a1 : NEG_SLOPE * a1;
    a2 = a2 > 0.f ? a2 : NEG_SLOPE * a2;
    a3 = a3 > 0.f ? a3 : NEG_SLOPE * a3;
    plog[pos] = make_float4(a0, a1, a2, a3);
    prow[pos] = r;
}

// ---------------------------------------------------------------------------
// fused per-node softmax + aggregation + residual + ELU. One wave per node.
// emb is bf16; each lane handles channels 2*lane, 2*lane+1 (one dword load/edge).
__device__ __forceinline__ void online_upd(float& m, float& s, float l) {
    float nm = fmaxf(m, l);
    s = s * __expf(m - nm) + __expf(l - nm);
    m = nm;
}

__global__ __launch_bounds__(256) void k_fused(
    const unsigned int* __restrict__ offs, const float4* __restrict__ plog,
    const int* __restrict__ prow, const ushort_t* __restrict__ embh,
    float* __restrict__ out) {
    __shared__ float alds[4][16][4];
    __shared__ int   rlds[4][16];
    const int w    = threadIdx.x >> 6;
    const int lane = threadIdx.x & 63;
    const int c    = blockIdx.x * 4 + w;
    if (c >= N_NODES) return;

    const unsigned int start = offs[c], end = offs[c + 1];

    // phase A: online softmax stats
    float m0 = -1e30f, m1 = -1e30f, m2 = -1e30f, m3 = -1e30f;
    float s0 = 0.f, s1 = 0.f, s2 = 0.f, s3 = 0.f;
    for (unsigned int i = start + lane; i < end; i += 64) {
        float4 L = plog[i];
        online_upd(m0, s0, L.x);
        online_upd(m1, s1, L.y);
        online_upd(m2, s2, L.z);
        online_upd(m3, s3, L.w);
    }
#pragma unroll
    for (int off = 32; off >= 1; off >>= 1) {
        float mo, so, nm;
        mo = __shfl_xor(m0, off); so = __shfl_xor(s0, off);
        nm = fmaxf(m0, mo); s0 = s0 * __expf(m0 - nm) + so * __expf(mo - nm); m0 = nm;
        mo = __shfl_xor(m1, off); so = __shfl_xor(s1, off);
        nm = fmaxf(m1, mo); s1 = s1 * __expf(m1 - nm) + so * __expf(mo - nm); m1 = nm;
        mo = __shfl_xor(m2, off); so = __shfl_xor(s2, off);
        nm = fmaxf(m2, mo); s2 = s2 * __expf(m2 - nm) + so * __expf(mo - nm); m2 = nm;
        mo = __shfl_xor(m3, off); so = __shfl_xor(s3, off);
        nm = fmaxf(m3, mo); s3 = s3 * __expf(m3 - nm) + so * __expf(mo - nm); m3 = nm;
    }
    const bool hasE = end > start;
    const float i0 = hasE ? 1.f / s0 : 0.f;
    const float i1 = hasE ? 1.f / s1 : 0.f;
    const float i2 = hasE ? 1.f / s2 : 0.f;
    const float i3 = hasE ? 1.f / s3 : 0.f;

    // phase B: lane owns emb channels 2*lane, 2*lane+1 (same head h = lane>>4)
    const int hd = lane >> 4;
    float accA = 0.f, accB = 0.f;

    for (unsigned int base = start; base < end; base += 16) {
        int cnt = (int)min(16u, end - base);
        if (lane < cnt) {
            float4 L = plog[base + lane];
            alds[w][lane][0] = __expf(L.x - m0) * i0;
            alds[w][lane][1] = __expf(L.y - m1) * i1;
            alds[w][lane][2] = __expf(L.z - m2) * i2;
            alds[w][lane][3] = __expf(L.w - m3) * i3;
            rlds[w][lane] = prow[base + lane];
        }
        for (int j = 0; j < cnt; ++j) {
            int r = rlds[w][j];
            float al = alds[w][j][hd];
            unsigned int v = *(const unsigned int*)&embh[(size_t)r * C_DIM + lane * 2];
            float lo = __uint_as_float(v << 16);
            float hi = __uint_as_float(v & 0xffff0000u);
            accA = fmaf(al, lo, accA);
            accB = fmaf(al, hi, accB);
        }
    }

    // emb channel 2*lane = hd*32 + d, d = (2*lane)&31 -> out channel d*4+hd
    const int d  = (2 * lane) & 31;
    const int oA = d * 4 + hd;
    const int oB = oA + 4;
    size_t ob = (size_t)c * C_DIM;
    float x0 = out[ob + oA] + accA;
    float x1 = out[ob + oB] + accB;
    out[ob + oA] = x0 > 0.f ? x0 : expm1f(x0);
    out[ob + oB] = x1 > 0.f ? x1 : expm1f(x1);
}

// ---------------------------------------------------------------------------
extern "C" void kernel_launch(void* const* d_in, const int* in_sizes, int n_in,
                              void* d_out, int out_size, void* d_ws, size_t ws_size,
                              hipStream_t stream) {
    const float* h        = (const float*)d_in[0];
    const float* W        = (const float*)d_in[1];
    const float* edge_emb = (const float*)d_in[2];
    const float* Wr       = (const float*)d_in[3];
    const float* a_l      = (const float*)d_in[4];
    const float* a_r      = (const float*)d_in[5];
    const float* a_e      = (const float*)d_in[6];
    const float* res_W    = (const float*)d_in[7];
    const float* res_b    = (const float*)d_in[8];
    const int*   row      = (const int*)d_in[9];
    const int*   col      = (const int*)d_in[10];
    const int*   etype    = (const int*)d_in[11];
    float* out = (float*)d_out;

    // workspace layout (4-byte units); plog first for 16B alignment
    float* ws = (float*)d_ws;
    float4*       ws_plog  = (float4*)ws;                                   // E*4 floats
    float*        p        = ws + (size_t)N_EDGES * 4;
    ushort_t*     ws_embh  = (ushort_t*)p;                                  // N*C_DIM shorts
    p += (size_t)N_NODES * C_DIM / 2;
    float*        ws_hl    = p;  p += (size_t)N_NODES * HEADS;              // N*4
    float*        ws_hr    = p;  p += (size_t)N_NODES * HEADS;              // N*4
    float*        ws_het   = p;  p += 32;
    unsigned int* ws_offs  = (unsigned int*)p;                              // N+1
    unsigned int* ws_cur   = ws_offs + (N_NODES + 1);                       // N
    unsigned int* ws_cnt   = ws_cur + N_NODES;                              // N
    unsigned int* ws_bsum  = ws_cnt + N_NODES;                              // NBLK_SCAN
    int*          ws_prow  = (int*)(ws_bsum + NBLK_SCAN);                   // E
    short*        ws_wt    = (short*)(ws_prow + N_EDGES);                   // 256*256 bf16

    kz_init<<<(N_NODES + 255) / 256, 256, 0, stream>>>(ws_cnt);

    k_het<<<NUM_ETY, 256, 0, stream>>>(edge_emb, Wr, a_e, ws_het);

    kw_prep<<<256, 256, 0, stream>>>(W, res_W, ws_wt);

    k1_mfma<<<(N_NODES + M_TILE - 1) / M_TILE, 512, 0, stream>>>(
        h, ws_wt, res_b, a_l, a_r, ws_embh, ws_hl, ws_hr, out);

    b1_hist<<<(N_EDGES + 255) / 256, 256, 0, stream>>>(col, ws_cnt);

    bscan1<<<NBLK_SCAN, 256, 0, stream>>>(ws_cnt, ws_offs, ws_bsum);
    bscan2<<<1, 512, 0, stream>>>(ws_bsum);
    bscan3<<<(N_NODES + 255) / 256, 256, 0, stream>>>(ws_offs, ws_bsum, ws_cur);

    b4_scatter<<<(N_EDGES + 255) / 256, 256, 0, stream>>>(
        row, col, etype, ws_hl, ws_hr, ws_het, ws_cur, ws_plog, ws_prow);

    k_fused<<<(N_NODES + 3) / 4, 256, 0, stream>>>(
        ws_offs, ws_plog, ws_prow, ws_embh, out);
}

// Round 8
// 530.778 us; speedup vs baseline: 7.2190x; 1.0390x over previous
//
#include <hip/hip_runtime.h>
#include <hip/hip_bf16.h>
#include <math.h>

#define N_NODES   100000
#define N_EDGES   1600000
#define IN_DIM    256
#define OUT_DIM   32
#define HEADS     4
#define C_DIM     128      // OUT_DIM*HEADS
#define EDGE_DIM  64
#define NUM_ETY   8
#define NEG_SLOPE 0.2f
#define NBLK_SCAN 391      // ceil(N_NODES/256)
#define M_TILE    128
#define BSTRIDE   40       // B LDS row stride in shorts (padded: 2-way conflicts only)

typedef __attribute__((ext_vector_type(8))) short s8b;   // 8 bf16 (4 VGPRs)
typedef __attribute__((ext_vector_type(4))) float f32x4; // MFMA accumulator
typedef unsigned short ushort_t;

__device__ __forceinline__ short bfc(float x) {
    __hip_bfloat16 b = __float2bfloat16(x);   // HW RNE cvt
    return *reinterpret_cast<short*>(&b);
}

// ---------------------------------------------------------------------------
// kz: zero the degree counters
__global__ void kz_init(unsigned int* __restrict__ counts) {
    int i = blockIdx.x * blockDim.x + threadIdx.x;
    if (i < N_NODES) counts[i] = 0u;
}

// k_het: h_e_type[ty][hh] = sum_f a_e[hh][f] * sum_e edge_emb[ty][e]*Wr[ty][e][hh*64+f]
__global__ __launch_bounds__(256) void k_het(
    const float* __restrict__ edge_emb, const float* __restrict__ Wr,
    const float* __restrict__ a_e, float* __restrict__ h_et) {
    __shared__ float ee[EDGE_DIM];
    const int t = threadIdx.x;
    const int ty = blockIdx.x;
    if (t < EDGE_DIM) ee[t] = edge_emb[ty * EDGE_DIM + t];
    __syncthreads();
    const int hh = t >> 6, f = t & 63;
    float acc = 0.f;
#pragma unroll 8
    for (int e = 0; e < EDGE_DIM; ++e)
        acc += ee[e] * Wr[(size_t)(ty * EDGE_DIM + e) * (HEADS * EDGE_DIM) + hh * EDGE_DIM + f];
    acc *= a_e[hh * EDGE_DIM + f];
#pragma unroll
    for (int m = 32; m >= 1; m >>= 1) acc += __shfl_xor(acc, m);
    if (f == 0) h_et[ty * HEADS + hh] = acc;
}

// kw: transpose+convert [W | resW] (fp32, [k][c]) -> Wt bf16 [c][k]
__global__ void kw_prep(const float* __restrict__ W, const float* __restrict__ resW,
                        short* __restrict__ wt) {
    int idx = blockIdx.x * 256 + threadIdx.x;     // 65536 = 256k x 256c
    int k = idx >> 8, c = idx & 255;
    float v = (c < C_DIM) ? W[k * C_DIM + c] : resW[k * C_DIM + (c - C_DIM)];
    wt[c * IN_DIM + k] = bfc(v);
}

// ---------------------------------------------------------------------------
// K1 (MFMA v3): block = 512 thr (8 waves, 4M x 2N), tile M=128 x N=256, K=256.
// A read directly from global h (fp32 -> bf16 in regs, L1-resident);
// B (Wt) double-buffered in LDS. LDS total 40 KB -> high occupancy.
__global__ __launch_bounds__(512, 4) void k1_mfma(
    const float* __restrict__ h, const short* __restrict__ wt,
    const float* __restrict__ resb,
    const float* __restrict__ a_l, const float* __restrict__ a_r,
    ushort_t* __restrict__ embh, float* __restrict__ hl, float* __restrict__ hr,
    float* __restrict__ out) {
    __shared__ short bs[2][256 * BSTRIDE];         // 2 x 20 KB
    const int t  = threadIdx.x;
    const int n0 = blockIdx.x * M_TILE;
    const int cstage = t >> 1, hstage = t & 1;

    // --- stage B chunk 0 (cols 0..255 x k 0..31)
    {
        const s8b* src = (const s8b*)&wt[cstage * IN_DIM + hstage * 16];
        s8b v0 = src[0], v1 = src[1];
        *(s8b*)&bs[0][cstage * BSTRIDE + hstage * 16] = v0;
        *(s8b*)&bs[0][cstage * BSTRIDE + hstage * 16 + 8] = v1;
    }
    __syncthreads();

    const int lane = t & 63, w = t >> 6;
    const int wm = w >> 1;           // 0..3 -> rows wm*32..+31
    const int wn = w & 1;            // 0..1 -> cols wn*128..+127
    const int ln = lane & 15;        // A row low / B col low / D col
    const int kk = lane >> 4;        // k-group (0..3)

    // A source rows (clamped; rows >= N produce garbage that is never stored)
    const int gr0 = min(n0 + wm * 32 + ln, N_NODES - 1);
    const int gr1 = min(n0 + wm * 32 + 16 + ln, N_NODES - 1);
    const float* __restrict__ ha0 = &h[(size_t)gr0 * IN_DIM + kk * 8];
    const float* __restrict__ ha1 = &h[(size_t)gr1 * IN_DIM + kk * 8];

    f32x4 acc[2][8];
#pragma unroll
    for (int mf = 0; mf < 2; ++mf)
#pragma unroll
        for (int nf = 0; nf < 8; ++nf) acc[mf][nf] = (f32x4){0.f, 0.f, 0.f, 0.f};

    int cur = 0;
#pragma unroll
    for (int ks = 0; ks < 8; ++ks) {
        // issue next B-chunk global loads early (latency hides under MFMAs)
        s8b nb0 = {}, nb1 = {};
        if (ks < 7) {
            const s8b* src = (const s8b*)&wt[cstage * IN_DIM + (ks + 1) * 32 + hstage * 16];
            nb0 = src[0];
            nb1 = src[1];
        }

        // A fragments: global fp32 -> bf16 regs (HW cvt)
        float4 l0 = *(const float4*)&ha0[ks * 32];
        float4 h0 = *(const float4*)&ha0[ks * 32 + 4];
        float4 l1 = *(const float4*)&ha1[ks * 32];
        float4 h1 = *(const float4*)&ha1[ks * 32 + 4];
        s8b a0, a1;
        a0[0] = bfc(l0.x); a0[1] = bfc(l0.y); a0[2] = bfc(l0.z); a0[3] = bfc(l0.w);
        a0[4] = bfc(h0.x); a0[5] = bfc(h0.y); a0[6] = bfc(h0.z); a0[7] = bfc(h0.w);
        a1[0] = bfc(l1.x); a1[1] = bfc(l1.y); a1[2] = bfc(l1.z); a1[3] = bfc(l1.w);
        a1[4] = bfc(h1.x); a1[5] = bfc(h1.y); a1[6] = bfc(h1.z); a1[7] = bfc(h1.w);

        // B fragments (8 n-frags) + MFMAs
#pragma unroll
        for (int nf = 0; nf < 8; ++nf) {
            int c = wn * 128 + nf * 16 + ln;
            s8b b = *(const s8b*)&bs[cur][c * BSTRIDE + kk * 8];
            acc[0][nf] = __builtin_amdgcn_mfma_f32_16x16x32_bf16(a0, b, acc[0][nf], 0, 0, 0);
            acc[1][nf] = __builtin_amdgcn_mfma_f32_16x16x32_bf16(a1, b, acc[1][nf], 0, 0, 0);
        }

        if (ks < 7) {
            *(s8b*)&bs[cur ^ 1][cstage * BSTRIDE + hstage * 16] = nb0;
            *(s8b*)&bs[cur ^ 1][cstage * BSTRIDE + hstage * 16 + 8] = nb1;
        }
        __syncthreads();
        cur ^= 1;
    }

    // --- epilogue. D layout: col = ln, row = kk*4 + reg
    if (wn == 0) {
        // cols 0..127 -> emb (bf16)
#pragma unroll
        for (int mf = 0; mf < 2; ++mf)
#pragma unroll
            for (int nf = 0; nf < 8; ++nf) {
                int col = nf * 16 + ln;
#pragma unroll
                for (int r = 0; r < 4; ++r) {
                    int nd = n0 + wm * 32 + mf * 16 + kk * 4 + r;
                    if (nd < N_NODES)
                        embh[(size_t)nd * C_DIM + col] = (ushort_t)bfc(acc[mf][nf][r]);
                }
            }
        // hl/hr from fp32 accumulators: head hh = frags 2hh, 2hh+1
#pragma unroll
        for (int mf = 0; mf < 2; ++mf)
#pragma unroll
            for (int hh = 0; hh < HEADS; ++hh) {
                float al0 = a_l[hh * 32 + ln], al1 = a_l[hh * 32 + 16 + ln];
                float ar0 = a_r[hh * 32 + ln], ar1 = a_r[hh * 32 + 16 + ln];
#pragma unroll
                for (int r = 0; r < 4; ++r) {
                    float pl = al0 * acc[mf][2 * hh][r] + al1 * acc[mf][2 * hh + 1][r];
                    float pr = ar0 * acc[mf][2 * hh][r] + ar1 * acc[mf][2 * hh + 1][r];
#pragma unroll
                    for (int m = 8; m >= 1; m >>= 1) {
                        pl += __shfl_xor(pl, m);
                        pr += __shfl_xor(pr, m);
                    }
                    int nd = n0 + wm * 32 + mf * 16 + kk * 4 + r;
                    if (ln == 0 && nd < N_NODES) {
                        hl[nd * HEADS + hh] = pl;
                        hr[nd * HEADS + hh] = pr;
                    }
                }
            }
    } else {
        // cols 128..255 -> out = res + b
#pragma unroll
        for (int mf = 0; mf < 2; ++mf)
#pragma unroll
            for (int nf = 0; nf < 8; ++nf) {
                int col = nf * 16 + ln;          // out channel
                float rb = resb[col];
#pragma unroll
                for (int r = 0; r < 4; ++r) {
                    int nd = n0 + wm * 32 + mf * 16 + kk * 4 + r;
                    if (nd < N_NODES) out[(size_t)nd * C_DIM + col] = acc[mf][nf][r] + rb;
                }
            }
    }
}

// ---------------------------------------------------------------------------
// histogram of destination degrees
__global__ void b1_hist(const int* __restrict__ col, unsigned int* __restrict__ counts) {
    int e = blockIdx.x * blockDim.x + threadIdx.x;
    if (e < N_EDGES) atomicAdd(&counts[col[e]], 1u);
}

// two-level exclusive scan
__global__ __launch_bounds__(256) void bscan1(const unsigned int* __restrict__ counts,
                                              unsigned int* __restrict__ offs,
                                              unsigned int* __restrict__ bsum) {
    __shared__ unsigned int s[256];
    int t = threadIdx.x;
    int g = blockIdx.x * 256 + t;
    unsigned int v = (g < N_NODES) ? counts[g] : 0u;
    s[t] = v;
    __syncthreads();
    for (int off = 1; off < 256; off <<= 1) {
        unsigned int x = (t >= off) ? s[t - off] : 0u;
        __syncthreads();
        s[t] += x;
        __syncthreads();
    }
    if (g < N_NODES) offs[g] = s[t] - v;
    if (t == 255) bsum[blockIdx.x] = s[255];
}

__global__ __launch_bounds__(512) void bscan2(unsigned int* __restrict__ bsum) {
    __shared__ unsigned int s[512];
    int t = threadIdx.x;
    unsigned int v = (t < NBLK_SCAN) ? bsum[t] : 0u;
    s[t] = v;
    __syncthreads();
    for (int off = 1; off < 512; off <<= 1) {
        unsigned int x = (t >= off) ? s[t - off] : 0u;
        __syncthreads();
        s[t] += x;
        __syncthreads();
    }
    if (t < NBLK_SCAN) bsum[t] = s[t] - v;
}

__global__ void bscan3(unsigned int* __restrict__ offs, const unsigned int* __restrict__ bsum,
                       unsigned int* __restrict__ cursor) {
    int g = blockIdx.x * blockDim.x + threadIdx.x;
    if (g < N_NODES) {
        unsigned int o = offs[g] + bsum[g >> 8];
        offs[g] = o;
        cursor[g] = o;
    }
    if (g == 0) offs[N_NODES] = N_EDGES;
}

// ---------------------------------------------------------------------------
// scatter: place each edge in its destination bucket; precompute leaky logit
__global__ void b4_scatter(const int* __restrict__ row, const int* __restrict__ col,
                           const int* __restrict__ ety,
                           const float* __restrict__ hl, const float* __restrict__ hr,
                           const float* __restrict__ het,
                           unsigned int* __restrict__ cursor,
                           float4* __restrict__ plog, int* __restrict__ prow) {
    int e = blockIdx.x * blockDim.x + threadIdx.x;
    if (e >= N_EDGES) return;
    int r = row[e], c = col[e], ty = ety[e];
    unsigned int pos = atomicAdd(&cursor[c], 1u);
    float4 l  = *(const float4*)&hl[r * 4];
    float4 rr = *(const float4*)&hr[c * 4];
    float4 te = *(const float4*)&het[ty * 4];
    float a0 = l.x + rr.x + te.x;
    float a1 = l.y + rr.y + te.y;
    float a2 = l.z + rr.z + te.z;
    float a3 = l.w + rr.w + te.w;
    a0 = a0 > 0.f ? a0 : NEG_SLOPE * a0;
    a1 = a1 > 0.f ? a1 : NEG_SLOPE * a1;
    a2 = a2 > 0.f ? a2 : NEG_SLOPE * a2;
    a3 = a3 > 0.f ? a3 : NEG_SLOPE * a3;
    plog[pos] = make_float4(a0, a1, a2, a3);
    prow[pos] = r;
}

// ---------------------------------------------------------------------------
// fused per-node softmax + aggregation + residual + ELU. One wave per node.
__device__ __forceinline__ void online_upd(float& m, float& s, float l) {
    float nm = fmaxf(m, l);
    s = s * __expf(m - nm) + __expf(l - nm);
    m = nm;
}

__global__ __launch_bounds__(256) void k_fused(
    const unsigned int* __restrict__ offs, const float4* __restrict__ plog,
    const int* __restrict__ prow, const ushort_t* __restrict__ embh,
    float* __restrict__ out) {
    __shared__ float alds[4][16][4];
    __shared__ int   rlds[4][16];
    const int w    = threadIdx.x >> 6;
    const int lane = threadIdx.x & 63;
    const int c    = blockIdx.x * 4 + w;
    if (c >= N_NODES) return;

    const unsigned int start = offs[c], end = offs[c + 1];

    // phase A: online softmax stats
    float m0 = -1e30f, m1 = -1e30f, m2 = -1e30f, m3 = -1e30f;
    float s0 = 0.f, s1 = 0.f, s2 = 0.f, s3 = 0.f;
    for (unsigned int i = start + lane; i < end; i += 64) {
        float4 L = plog[i];
        online_upd(m0, s0, L.x);
        online_upd(m1, s1, L.y);
        online_upd(m2, s2, L.z);
        online_upd(m3, s3, L.w);
    }
#pragma unroll
    for (int off = 32; off >= 1; off >>= 1) {
        float mo, so, nm;
        mo = __shfl_xor(m0, off); so = __shfl_xor(s0, off);
        nm = fmaxf(m0, mo); s0 = s0 * __expf(m0 - nm) + so * __expf(mo - nm); m0 = nm;
        mo = __shfl_xor(m1, off); so = __shfl_xor(s1, off);
        nm = fmaxf(m1, mo); s1 = s1 * __expf(m1 - nm) + so * __expf(mo - nm); m1 = nm;
        mo = __shfl_xor(m2, off); so = __shfl_xor(s2, off);
        nm = fmaxf(m2, mo); s2 = s2 * __expf(m2 - nm) + so * __expf(mo - nm); m2 = nm;
        mo = __shfl_xor(m3, off); so = __shfl_xor(s3, off);
        nm = fmaxf(m3, mo); s3 = s3 * __expf(m3 - nm) + so * __expf(mo - nm); m3 = nm;
    }
    const bool hasE = end > start;
    const float i0 = hasE ? 1.f / s0 : 0.f;
    const float i1 = hasE ? 1.f / s1 : 0.f;
    const float i2 = hasE ? 1.f / s2 : 0.f;
    const float i3 = hasE ? 1.f / s3 : 0.f;

    // phase B: lane owns emb channels 2*lane, 2*lane+1 (same head h = lane>>4)
    const int hd = lane >> 4;
    float accA = 0.f, accB = 0.f;

    for (unsigned int base = start; base < end; base += 16) {
        int cnt = (int)min(16u, end - base);
        if (lane < cnt) {
            float4 L = plog[base + lane];
            alds[w][lane][0] = __expf(L.x - m0) * i0;
            alds[w][lane][1] = __expf(L.y - m1) * i1;
            alds[w][lane][2] = __expf(L.z - m2) * i2;
            alds[w][lane][3] = __expf(L.w - m3) * i3;
            rlds[w][lane] = prow[base + lane];
        }
        for (int j = 0; j < cnt; ++j) {
            int r = rlds[w][j];
            float al = alds[w][j][hd];
            unsigned int v = *(const unsigned int*)&embh[(size_t)r * C_DIM + lane * 2];
            float lo = __uint_as_float(v << 16);
            float hi = __uint_as_float(v & 0xffff0000u);
            accA = fmaf(al, lo, accA);
            accB = fmaf(al, hi, accB);
        }
    }

    // emb channel 2*lane = hd*32 + d, d = (2*lane)&31 -> out channel d*4+hd
    const int d  = (2 * lane) & 31;
    const int oA = d * 4 + hd;
    const int oB = oA + 4;
    size_t ob = (size_t)c * C_DIM;
    float x0 = out[ob + oA] + accA;
    float x1 = out[ob + oB] + accB;
    out[ob + oA] = x0 > 0.f ? x0 : expm1f(x0);
    out[ob + oB] = x1 > 0.f ? x1 : expm1f(x1);
}

// ---------------------------------------------------------------------------
extern "C" void kernel_launch(void* const* d_in, const int* in_sizes, int n_in,
                              void* d_out, int out_size, void* d_ws, size_t ws_size,
                              hipStream_t stream) {
    const float* h        = (const float*)d_in[0];
    const float* W        = (const float*)d_in[1];
    const float* edge_emb = (const float*)d_in[2];
    const float* Wr       = (const float*)d_in[3];
    const float* a_l      = (const float*)d_in[4];
    const float* a_r      = (const float*)d_in[5];
    const float* a_e      = (const float*)d_in[6];
    const float* res_W    = (const float*)d_in[7];
    const float* res_b    = (const float*)d_in[8];
    const int*   row      = (const int*)d_in[9];
    const int*   col      = (const int*)d_in[10];
    const int*   etype    = (const int*)d_in[11];
    float* out = (float*)d_out;

    // workspace layout (4-byte units); plog first for 16B alignment
    float* ws = (float*)d_ws;
    float4*       ws_plog  = (float4*)ws;                                   // E*4 floats
    float*        p        = ws + (size_t)N_EDGES * 4;
    ushort_t*     ws_embh  = (ushort_t*)p;                                  // N*C_DIM shorts
    p += (size_t)N_NODES * C_DIM / 2;
    float*        ws_hl    = p;  p += (size_t)N_NODES * HEADS;              // N*4
    float*        ws_hr    = p;  p += (size_t)N_NODES * HEADS;              // N*4
    float*        ws_het   = p;  p += 32;
    unsigned int* ws_offs  = (unsigned int*)p;                              // N+1
    unsigned int* ws_cur   = ws_offs + (N_NODES + 1);                       // N
    unsigned int* ws_cnt   = ws_cur + N_NODES;                              // N
    unsigned int* ws_bsum  = ws_cnt + N_NODES;                              // NBLK_SCAN
    int*          ws_prow  = (int*)(ws_bsum + NBLK_SCAN);                   // E
    short*        ws_wt    = (short*)(ws_prow + N_EDGES);                   // 256*256 bf16

    kz_init<<<(N_NODES + 255) / 256, 256, 0, stream>>>(ws_cnt);

    k_het<<<NUM_ETY, 256, 0, stream>>>(edge_emb, Wr, a_e, ws_het);

    kw_prep<<<256, 256, 0, stream>>>(W, res_W, ws_wt);

    k1_mfma<<<(N_NODES + M_TILE - 1) / M_TILE, 512, 0, stream>>>(
        h, ws_wt, res_b, a_l, a_r, ws_embh, ws_hl, ws_hr, out);

    b1_hist<<<(N_EDGES + 255) / 256, 256, 0, stream>>>(col, ws_cnt);

    bscan1<<<NBLK_SCAN, 256, 0, stream>>>(ws_cnt, ws_offs, ws_bsum);
    bscan2<<<1, 512, 0, stream>>>(ws_bsum);
    bscan3<<<(N_NODES + 255) / 256, 256, 0, stream>>>(ws_offs, ws_bsum, ws_cur);

    b4_scatter<<<(N_EDGES + 255) / 256, 256, 0, stream>>>(
        row, col, etype, ws_hl, ws_hr, ws_het, ws_cur, ws_plog, ws_prow);

    k_fused<<<(N_NODES + 3) / 4, 256, 0, stream>>>(
        ws_offs, ws_plog, ws_prow, ws_embh, out);
}

// Round 9
// 529.098 us; speedup vs baseline: 7.2419x; 1.0032x over previous
//
#include <hip/hip_runtime.h>
#include <hip/hip_bf16.h>
#include <math.h>

#define N_NODES   100000
#define N_EDGES   1600000
#define IN_DIM    256
#define OUT_DIM   32
#define HEADS     4
#define C_DIM     128      // OUT_DIM*HEADS
#define EDGE_DIM  64
#define NUM_ETY   8
#define NEG_SLOPE 0.2f
#define NBLK_SCAN 391      // ceil(N_NODES/256)
#define M_TILE    128
#define BSTRIDE   40       // B LDS row stride in shorts (padded: 2-way conflicts only)

typedef __attribute__((ext_vector_type(8))) short s8b;   // 8 bf16 (4 VGPRs)
typedef __attribute__((ext_vector_type(4))) float f32x4; // MFMA accumulator
typedef unsigned short ushort_t;

__device__ __forceinline__ short bfc(float x) {
    __hip_bfloat16 b = __float2bfloat16(x);   // HW RNE cvt
    return *reinterpret_cast<short*>(&b);
}

// ---------------------------------------------------------------------------
// kz: zero the degree counters
__global__ void kz_init(unsigned int* __restrict__ counts) {
    int i = blockIdx.x * blockDim.x + threadIdx.x;
    if (i < N_NODES) counts[i] = 0u;
}

// k_het: h_e_type[ty][hh] = sum_f a_e[hh][f] * sum_e edge_emb[ty][e]*Wr[ty][e][hh*64+f]
__global__ __launch_bounds__(256) void k_het(
    const float* __restrict__ edge_emb, const float* __restrict__ Wr,
    const float* __restrict__ a_e, float* __restrict__ h_et) {
    __shared__ float ee[EDGE_DIM];
    const int t = threadIdx.x;
    const int ty = blockIdx.x;
    if (t < EDGE_DIM) ee[t] = edge_emb[ty * EDGE_DIM + t];
    __syncthreads();
    const int hh = t >> 6, f = t & 63;
    float acc = 0.f;
#pragma unroll 8
    for (int e = 0; e < EDGE_DIM; ++e)
        acc += ee[e] * Wr[(size_t)(ty * EDGE_DIM + e) * (HEADS * EDGE_DIM) + hh * EDGE_DIM + f];
    acc *= a_e[hh * EDGE_DIM + f];
#pragma unroll
    for (int m = 32; m >= 1; m >>= 1) acc += __shfl_xor(acc, m);
    if (f == 0) h_et[ty * HEADS + hh] = acc;
}

// kw: transpose+convert [W | resW] (fp32, [k][c]) -> Wt bf16 [c][k]
__global__ void kw_prep(const float* __restrict__ W, const float* __restrict__ resW,
                        short* __restrict__ wt) {
    int idx = blockIdx.x * 256 + threadIdx.x;     // 65536 = 256k x 256c
    int k = idx >> 8, c = idx & 255;
    float v = (c < C_DIM) ? W[k * C_DIM + c] : resW[k * C_DIM + (c - C_DIM)];
    wt[c * IN_DIM + k] = bfc(v);
}

// ---------------------------------------------------------------------------
// K1 (MFMA v4): block = 256 thr (4 waves: 2M x 2N), tile M=128 x N=256, K=256.
// Each wave: 4 m-frags x 8 n-frags -> each B ds_read feeds 4 MFMAs (LDS no
// longer the cap). A direct from global (fp32->bf16 regs); B dbuf in LDS.
__global__ __launch_bounds__(256, 2) void k1_mfma(
    const float* __restrict__ h, const short* __restrict__ wt,
    const float* __restrict__ resb,
    const float* __restrict__ a_l, const float* __restrict__ a_r,
    ushort_t* __restrict__ embh, float* __restrict__ hl, float* __restrict__ hr,
    float* __restrict__ out) {
    __shared__ short bs[2][256 * BSTRIDE];         // 2 x 20 KB
    const int t  = threadIdx.x;
    const int n0 = blockIdx.x * M_TILE;

    // --- stage B chunk 0: thread t = col t, k 0..31 (4 x s8b)
    {
#pragma unroll
        for (int j = 0; j < 4; ++j) {
            s8b v = *(const s8b*)&wt[t * IN_DIM + j * 8];
            *(s8b*)&bs[0][t * BSTRIDE + j * 8] = v;
        }
    }
    __syncthreads();

    const int lane = t & 63, w = t >> 6;
    const int wm = w >> 1;           // 0..1 -> rows wm*64..+63
    const int wn = w & 1;            // 0..1 -> cols wn*128..+127
    const int ln = lane & 15;        // A row low / B col low / D col
    const int kk = lane >> 4;        // k-group (0..3)

    // A source rows (4 m-frags; clamped rows never stored)
    const float* __restrict__ ha[4];
#pragma unroll
    for (int mf = 0; mf < 4; ++mf) {
        int gr = min(n0 + wm * 64 + mf * 16 + ln, N_NODES - 1);
        ha[mf] = &h[(size_t)gr * IN_DIM + kk * 8];
    }

    f32x4 acc[4][8];
#pragma unroll
    for (int mf = 0; mf < 4; ++mf)
#pragma unroll
        for (int nf = 0; nf < 8; ++nf) acc[mf][nf] = (f32x4){0.f, 0.f, 0.f, 0.f};

    int cur = 0;
#pragma unroll
    for (int ks = 0; ks < 8; ++ks) {
        // next B-chunk prefetch into regs (latency hides under MFMAs)
        s8b nb0 = {}, nb1 = {}, nb2 = {}, nb3 = {};
        if (ks < 7) {
            const short* src = &wt[t * IN_DIM + (ks + 1) * 32];
            nb0 = *(const s8b*)&src[0];
            nb1 = *(const s8b*)&src[8];
            nb2 = *(const s8b*)&src[16];
            nb3 = *(const s8b*)&src[24];
        }

        // A fragments: global fp32 -> bf16 regs (HW cvt)
        s8b a[4];
#pragma unroll
        for (int mf = 0; mf < 4; ++mf) {
            float4 lo = *(const float4*)&ha[mf][ks * 32];
            float4 hi = *(const float4*)&ha[mf][ks * 32 + 4];
            a[mf][0] = bfc(lo.x); a[mf][1] = bfc(lo.y);
            a[mf][2] = bfc(lo.z); a[mf][3] = bfc(lo.w);
            a[mf][4] = bfc(hi.x); a[mf][5] = bfc(hi.y);
            a[mf][6] = bfc(hi.z); a[mf][7] = bfc(hi.w);
        }

        // B fragments (8 n-frags), each feeds 4 MFMAs
#pragma unroll
        for (int nf = 0; nf < 8; ++nf) {
            int c = wn * 128 + nf * 16 + ln;
            s8b b = *(const s8b*)&bs[cur][c * BSTRIDE + kk * 8];
            acc[0][nf] = __builtin_amdgcn_mfma_f32_16x16x32_bf16(a[0], b, acc[0][nf], 0, 0, 0);
            acc[1][nf] = __builtin_amdgcn_mfma_f32_16x16x32_bf16(a[1], b, acc[1][nf], 0, 0, 0);
            acc[2][nf] = __builtin_amdgcn_mfma_f32_16x16x32_bf16(a[2], b, acc[2][nf], 0, 0, 0);
            acc[3][nf] = __builtin_amdgcn_mfma_f32_16x16x32_bf16(a[3], b, acc[3][nf], 0, 0, 0);
        }

        if (ks < 7) {
            short* dst = &bs[cur ^ 1][t * BSTRIDE];
            *(s8b*)&dst[0]  = nb0;
            *(s8b*)&dst[8]  = nb1;
            *(s8b*)&dst[16] = nb2;
            *(s8b*)&dst[24] = nb3;
        }
        __syncthreads();
        cur ^= 1;
    }

    // --- epilogue. D layout: col = ln, row = kk*4 + reg
    if (wn == 0) {
        // cols 0..127 -> emb (bf16)
#pragma unroll
        for (int mf = 0; mf < 4; ++mf)
#pragma unroll
            for (int nf = 0; nf < 8; ++nf) {
                int col = nf * 16 + ln;
#pragma unroll
                for (int r = 0; r < 4; ++r) {
                    int nd = n0 + wm * 64 + mf * 16 + kk * 4 + r;
                    if (nd < N_NODES)
                        embh[(size_t)nd * C_DIM + col] = (ushort_t)bfc(acc[mf][nf][r]);
                }
            }
        // hl/hr from fp32 accumulators: head hh = frags 2hh, 2hh+1
#pragma unroll
        for (int mf = 0; mf < 4; ++mf)
#pragma unroll
            for (int hh = 0; hh < HEADS; ++hh) {
                float al0 = a_l[hh * 32 + ln], al1 = a_l[hh * 32 + 16 + ln];
                float ar0 = a_r[hh * 32 + ln], ar1 = a_r[hh * 32 + 16 + ln];
#pragma unroll
                for (int r = 0; r < 4; ++r) {
                    float pl = al0 * acc[mf][2 * hh][r] + al1 * acc[mf][2 * hh + 1][r];
                    float pr = ar0 * acc[mf][2 * hh][r] + ar1 * acc[mf][2 * hh + 1][r];
#pragma unroll
                    for (int m = 8; m >= 1; m >>= 1) {
                        pl += __shfl_xor(pl, m);
                        pr += __shfl_xor(pr, m);
                    }
                    int nd = n0 + wm * 64 + mf * 16 + kk * 4 + r;
                    if (ln == 0 && nd < N_NODES) {
                        hl[nd * HEADS + hh] = pl;
                        hr[nd * HEADS + hh] = pr;
                    }
                }
            }
    } else {
        // cols 128..255 -> out = res + b
#pragma unroll
        for (int mf = 0; mf < 4; ++mf)
#pragma unroll
            for (int nf = 0; nf < 8; ++nf) {
                int col = nf * 16 + ln;          // out channel
                float rb = resb[col];
#pragma unroll
                for (int r = 0; r < 4; ++r) {
                    int nd = n0 + wm * 64 + mf * 16 + kk * 4 + r;
                    if (nd < N_NODES) out[(size_t)nd * C_DIM + col] = acc[mf][nf][r] + rb;
                }
            }
    }
}

// ---------------------------------------------------------------------------
// histogram of destination degrees
__global__ void b1_hist(const int* __restrict__ col, unsigned int* __restrict__ counts) {
    int e = blockIdx.x * blockDim.x + threadIdx.x;
    if (e < N_EDGES) atomicAdd(&counts[col[e]], 1u);
}

// two-level exclusive scan
__global__ __launch_bounds__(256) void bscan1(const unsigned int* __restrict__ counts,
                                              unsigned int* __restrict__ offs,
                                              unsigned int* __restrict__ bsum) {
    __shared__ unsigned int s[256];
    int t = threadIdx.x;
    int g = blockIdx.x * 256 + t;
    unsigned int v = (g < N_NODES) ? counts[g] : 0u;
    s[t] = v;
    __syncthreads();
    for (int off = 1; off < 256; off <<= 1) {
        unsigned int x = (t >= off) ? s[t - off] : 0u;
        __syncthreads();
        s[t] += x;
        __syncthreads();
    }
    if (g < N_NODES) offs[g] = s[t] - v;
    if (t == 255) bsum[blockIdx.x] = s[255];
}

__global__ __launch_bounds__(512) void bscan2(unsigned int* __restrict__ bsum) {
    __shared__ unsigned int s[512];
    int t = threadIdx.x;
    unsigned int v = (t < NBLK_SCAN) ? bsum[t] : 0u;
    s[t] = v;
    __syncthreads();
    for (int off = 1; off < 512; off <<= 1) {
        unsigned int x = (t >= off) ? s[t - off] : 0u;
        __syncthreads();
        s[t] += x;
        __syncthreads();
    }
    if (t < NBLK_SCAN) bsum[t] = s[t] - v;
}

__global__ void bscan3(unsigned int* __restrict__ offs, const unsigned int* __restrict__ bsum,
                       unsigned int* __restrict__ cursor) {
    int g = blockIdx.x * blockDim.x + threadIdx.x;
    if (g < N_NODES) {
        unsigned int o = offs[g] + bsum[g >> 8];
        offs[g] = o;
        cursor[g] = o;
    }
    if (g == 0) offs[N_NODES] = N_EDGES;
}

// ---------------------------------------------------------------------------
// scatter: place each edge in its destination bucket; precompute leaky logit
__global__ void b4_scatter(const int* __restrict__ row, const int* __restrict__ col,
                           const int* __restrict__ ety,
                           const float* __restrict__ hl, const float* __restrict__ hr,
                           const float* __restrict__ het,
                           unsigned int* __restrict__ cursor,
                           float4* __restrict__ plog, int* __restrict__ prow) {
    int e = blockIdx.x * blockDim.x + threadIdx.x;
    if (e >= N_EDGES) return;
    int r = row[e], c = col[e], ty = ety[e];
    unsigned int pos = atomicAdd(&cursor[c], 1u);
    float4 l  = *(const float4*)&hl[r * 4];
    float4 rr = *(const float4*)&hr[c * 4];
    float4 te = *(const float4*)&het[ty * 4];
    float a0 = l.x + rr.x + te.x;
    float a1 = l.y + rr.y + te.y;
    float a2 = l.z + rr.z + te.z;
    float a3 = l.w + rr.w + te.w;
    a0 = a0 > 0.f ? a0 : NEG_SLOPE * a0;
    a1 = a1 > 0.f ? a1 : NEG_SLOPE * a1;
    a2 = a2 > 0.f ? a2 : NEG_SLOPE * a2;
    a3 = a3 > 0.f ? a3 : NEG_SLOPE * a3;
    plog[pos] = make_float4(a0, a1, a2, a3);
    prow[pos] = r;
}

// ---------------------------------------------------------------------------
// fused per-node softmax + aggregation + residual + ELU. One wave per node.
__device__ __forceinline__ void online_upd(float& m, float& s, float l) {
    float nm = fmaxf(m, l);
    s = s * __expf(m - nm) + __expf(l - nm);
    m = nm;
}

__global__ __launch_bounds__(256) void k_fused(
    const unsigned int* __restrict__ offs, const float4* __restrict__ plog,
    const int* __restrict__ prow, const ushort_t* __restrict__ embh,
    float* __restrict__ out) {
    __shared__ float alds[4][16][4];
    __shared__ int   rlds[4][16];
    const int w    = threadIdx.x >> 6;
    const int lane = threadIdx.x & 63;
    const int c    = blockIdx.x * 4 + w;
    if (c >= N_NODES) return;

    const unsigned int start = offs[c], end = offs[c + 1];

    // phase A: online softmax stats
    float m0 = -1e30f, m1 = -1e30f, m2 = -1e30f, m3 = -1e30f;
    float s0 = 0.f, s1 = 0.f, s2 = 0.f, s3 = 0.f;
    for (unsigned int i = start + lane; i < end; i += 64) {
        float4 L = plog[i];
        online_upd(m0, s0, L.x);
        online_upd(m1, s1, L.y);
        online_upd(m2, s2, L.z);
        online_upd(m3, s3, L.w);
    }
#pragma unroll
    for (int off = 32; off >= 1; off >>= 1) {
        float mo, so, nm;
        mo = __shfl_xor(m0, off); so = __shfl_xor(s0, off);
        nm = fmaxf(m0, mo); s0 = s0 * __expf(m0 - nm) + so * __expf(mo - nm); m0 = nm;
        mo = __shfl_xor(m1, off); so = __shfl_xor(s1, off);
        nm = fmaxf(m1, mo); s1 = s1 * __expf(m1 - nm) + so * __expf(mo - nm); m1 = nm;
        mo = __shfl_xor(m2, off); so = __shfl_xor(s2, off);
        nm = fmaxf(m2, mo); s2 = s2 * __expf(m2 - nm) + so * __expf(mo - nm); m2 = nm;
        mo = __shfl_xor(m3, off); so = __shfl_xor(s3, off);
        nm = fmaxf(m3, mo); s3 = s3 * __expf(m3 - nm) + so * __expf(mo - nm); m3 = nm;
    }
    const bool hasE = end > start;
    const float i0 = hasE ? 1.f / s0 : 0.f;
    const float i1 = hasE ? 1.f / s1 : 0.f;
    const float i2 = hasE ? 1.f / s2 : 0.f;
    const float i3 = hasE ? 1.f / s3 : 0.f;

    // phase B: lane owns emb channels 2*lane, 2*lane+1 (same head h = lane>>4)
    const int hd = lane >> 4;
    float accA = 0.f, accB = 0.f;

    for (unsigned int base = start; base < end; base += 16) {
        int cnt = (int)min(16u, end - base);
        if (lane < cnt) {
            float4 L = plog[base + lane];
            alds[w][lane][0] = __expf(L.x - m0) * i0;
            alds[w][lane][1] = __expf(L.y - m1) * i1;
            alds[w][lane][2] = __expf(L.z - m2) * i2;
            alds[w][lane][3] = __expf(L.w - m3) * i3;
            rlds[w][lane] = prow[base + lane];
        }
        for (int j = 0; j < cnt; ++j) {
            int r = rlds[w][j];
            float al = alds[w][j][hd];
            unsigned int v = *(const unsigned int*)&embh[(size_t)r * C_DIM + lane * 2];
            float lo = __uint_as_float(v << 16);
            float hi = __uint_as_float(v & 0xffff0000u);
            accA = fmaf(al, lo, accA);
            accB = fmaf(al, hi, accB);
        }
    }

    // emb channel 2*lane = hd*32 + d, d = (2*lane)&31 -> out channel d*4+hd
    const int d  = (2 * lane) & 31;
    const int oA = d * 4 + hd;
    const int oB = oA + 4;
    size_t ob = (size_t)c * C_DIM;
    float x0 = out[ob + oA] + accA;
    float x1 = out[ob + oB] + accB;
    out[ob + oA] = x0 > 0.f ? x0 : expm1f(x0);
    out[ob + oB] = x1 > 0.f ? x1 : expm1f(x1);
}

// ---------------------------------------------------------------------------
extern "C" void kernel_launch(void* const* d_in, const int* in_sizes, int n_in,
                              void* d_out, int out_size, void* d_ws, size_t ws_size,
                              hipStream_t stream) {
    const float* h        = (const float*)d_in[0];
    const float* W        = (const float*)d_in[1];
    const float* edge_emb = (const float*)d_in[2];
    const float* Wr       = (const float*)d_in[3];
    const float* a_l      = (const float*)d_in[4];
    const float* a_r      = (const float*)d_in[5];
    const float* a_e      = (const float*)d_in[6];
    const float* res_W    = (const float*)d_in[7];
    const float* res_b    = (const float*)d_in[8];
    const int*   row      = (const int*)d_in[9];
    const int*   col      = (const int*)d_in[10];
    const int*   etype    = (const int*)d_in[11];
    float* out = (float*)d_out;

    // workspace layout (4-byte units); plog first for 16B alignment
    float* ws = (float*)d_ws;
    float4*       ws_plog  = (float4*)ws;                                   // E*4 floats
    float*        p        = ws + (size_t)N_EDGES * 4;
    ushort_t*     ws_embh  = (ushort_t*)p;                                  // N*C_DIM shorts
    p += (size_t)N_NODES * C_DIM / 2;
    float*        ws_hl    = p;  p += (size_t)N_NODES * HEADS;              // N*4
    float*        ws_hr    = p;  p += (size_t)N_NODES * HEADS;              // N*4
    float*        ws_het   = p;  p += 32;
    unsigned int* ws_offs  = (unsigned int*)p;                              // N+1
    unsigned int* ws_cur   = ws_offs + (N_NODES + 1);                       // N
    unsigned int* ws_cnt   = ws_cur + N_NODES;                              // N
    unsigned int* ws_bsum  = ws_cnt + N_NODES;                              // NBLK_SCAN
    int*          ws_prow  = (int*)(ws_bsum + NBLK_SCAN);                   // E
    short*        ws_wt    = (short*)(ws_prow + N_EDGES);                   // 256*256 bf16

    kz_init<<<(N_NODES + 255) / 256, 256, 0, stream>>>(ws_cnt);

    k_het<<<NUM_ETY, 256, 0, stream>>>(edge_emb, Wr, a_e, ws_het);

    kw_prep<<<256, 256, 0, stream>>>(W, res_W, ws_wt);

    k1_mfma<<<(N_NODES + M_TILE - 1) / M_TILE, 256, 0, stream>>>(
        h, ws_wt, res_b, a_l, a_r, ws_embh, ws_hl, ws_hr, out);

    b1_hist<<<(N_EDGES + 255) / 256, 256, 0, stream>>>(col, ws_cnt);

    bscan1<<<NBLK_SCAN, 256, 0, stream>>>(ws_cnt, ws_offs, ws_bsum);
    bscan2<<<1, 512, 0, stream>>>(ws_bsum);
    bscan3<<<(N_NODES + 255) / 256, 256, 0, stream>>>(ws_offs, ws_bsum, ws_cur);

    b4_scatter<<<(N_EDGES + 255) / 256, 256, 0, stream>>>(
        row, col, etype, ws_hl, ws_hr, ws_het, ws_cur, ws_plog, ws_prow);

    k_fused<<<(N_NODES + 3) / 4, 256, 0, stream>>>(
        ws_offs, ws_plog, ws_prow, ws_embh, out);
}

// Round 10
// 511.275 us; speedup vs baseline: 7.4944x; 1.0349x over previous
//
#include <hip/hip_runtime.h>
#include <hip/hip_bf16.h>
#include <math.h>

#define N_NODES   100000
#define N_EDGES   1600000
#define IN_DIM    256
#define OUT_DIM   32
#define HEADS     4
#define C_DIM     128      // OUT_DIM*HEADS
#define EDGE_DIM  64
#define NUM_ETY   8
#define NEG_SLOPE 0.2f
#define NBLK_SCAN 391      // ceil(N_NODES/256)
#define M_TILE    128
#define BSTRIDE   40       // B LDS row stride in shorts (padded: 2-way conflicts only)

typedef __attribute__((ext_vector_type(8))) short s8b;   // 8 bf16 (4 VGPRs)
typedef __attribute__((ext_vector_type(4))) float f32x4; // MFMA accumulator
typedef unsigned short ushort_t;

__device__ __forceinline__ short bfc(float x) {
    __hip_bfloat16 b = __float2bfloat16(x);   // HW RNE cvt
    return *reinterpret_cast<short*>(&b);
}
__device__ __forceinline__ float uasf(unsigned int u) { return __uint_as_float(u); }

// ---------------------------------------------------------------------------
// kz: zero the degree counters
__global__ void kz_init(unsigned int* __restrict__ counts) {
    int i = blockIdx.x * blockDim.x + threadIdx.x;
    if (i < N_NODES) counts[i] = 0u;
}

// k_het: h_e_type[ty][hh] = sum_f a_e[hh][f] * sum_e edge_emb[ty][e]*Wr[ty][e][hh*64+f]
__global__ __launch_bounds__(256) void k_het(
    const float* __restrict__ edge_emb, const float* __restrict__ Wr,
    const float* __restrict__ a_e, float* __restrict__ h_et) {
    __shared__ float ee[EDGE_DIM];
    const int t = threadIdx.x;
    const int ty = blockIdx.x;
    if (t < EDGE_DIM) ee[t] = edge_emb[ty * EDGE_DIM + t];
    __syncthreads();
    const int hh = t >> 6, f = t & 63;
    float acc = 0.f;
#pragma unroll 8
    for (int e = 0; e < EDGE_DIM; ++e)
        acc += ee[e] * Wr[(size_t)(ty * EDGE_DIM + e) * (HEADS * EDGE_DIM) + hh * EDGE_DIM + f];
    acc *= a_e[hh * EDGE_DIM + f];
#pragma unroll
    for (int m = 32; m >= 1; m >>= 1) acc += __shfl_xor(acc, m);
    if (f == 0) h_et[ty * HEADS + hh] = acc;
}

// kw: transpose+convert [W | resW] (fp32, [k][c]) -> Wt bf16 [c][k]
__global__ void kw_prep(const float* __restrict__ W, const float* __restrict__ resW,
                        short* __restrict__ wt) {
    int idx = blockIdx.x * 256 + threadIdx.x;     // 65536 = 256k x 256c
    int k = idx >> 8, c = idx & 255;
    float v = (c < C_DIM) ? W[k * C_DIM + c] : resW[k * C_DIM + (c - C_DIM)];
    wt[c * IN_DIM + k] = bfc(v);
}

// ---------------------------------------------------------------------------
// K1 (MFMA v4): block = 256 thr (4 waves: 2M x 2N), tile M=128 x N=256, K=256.
__global__ __launch_bounds__(256, 2) void k1_mfma(
    const float* __restrict__ h, const short* __restrict__ wt,
    const float* __restrict__ resb,
    const float* __restrict__ a_l, const float* __restrict__ a_r,
    ushort_t* __restrict__ embh, float* __restrict__ hl, float* __restrict__ hr,
    float* __restrict__ out) {
    __shared__ short bs[2][256 * BSTRIDE];         // 2 x 20 KB
    const int t  = threadIdx.x;
    const int n0 = blockIdx.x * M_TILE;

    // --- stage B chunk 0: thread t = col t, k 0..31 (4 x s8b)
    {
#pragma unroll
        for (int j = 0; j < 4; ++j) {
            s8b v = *(const s8b*)&wt[t * IN_DIM + j * 8];
            *(s8b*)&bs[0][t * BSTRIDE + j * 8] = v;
        }
    }
    __syncthreads();

    const int lane = t & 63, w = t >> 6;
    const int wm = w >> 1;           // 0..1 -> rows wm*64..+63
    const int wn = w & 1;            // 0..1 -> cols wn*128..+127
    const int ln = lane & 15;        // A row low / B col low / D col
    const int kk = lane >> 4;        // k-group (0..3)

    const float* __restrict__ ha[4];
#pragma unroll
    for (int mf = 0; mf < 4; ++mf) {
        int gr = min(n0 + wm * 64 + mf * 16 + ln, N_NODES - 1);
        ha[mf] = &h[(size_t)gr * IN_DIM + kk * 8];
    }

    f32x4 acc[4][8];
#pragma unroll
    for (int mf = 0; mf < 4; ++mf)
#pragma unroll
        for (int nf = 0; nf < 8; ++nf) acc[mf][nf] = (f32x4){0.f, 0.f, 0.f, 0.f};

    int cur = 0;
#pragma unroll
    for (int ks = 0; ks < 8; ++ks) {
        s8b nb0 = {}, nb1 = {}, nb2 = {}, nb3 = {};
        if (ks < 7) {
            const short* src = &wt[t * IN_DIM + (ks + 1) * 32];
            nb0 = *(const s8b*)&src[0];
            nb1 = *(const s8b*)&src[8];
            nb2 = *(const s8b*)&src[16];
            nb3 = *(const s8b*)&src[24];
        }

        s8b a[4];
#pragma unroll
        for (int mf = 0; mf < 4; ++mf) {
            float4 lo = *(const float4*)&ha[mf][ks * 32];
            float4 hi = *(const float4*)&ha[mf][ks * 32 + 4];
            a[mf][0] = bfc(lo.x); a[mf][1] = bfc(lo.y);
            a[mf][2] = bfc(lo.z); a[mf][3] = bfc(lo.w);
            a[mf][4] = bfc(hi.x); a[mf][5] = bfc(hi.y);
            a[mf][6] = bfc(hi.z); a[mf][7] = bfc(hi.w);
        }

#pragma unroll
        for (int nf = 0; nf < 8; ++nf) {
            int c = wn * 128 + nf * 16 + ln;
            s8b b = *(const s8b*)&bs[cur][c * BSTRIDE + kk * 8];
            acc[0][nf] = __builtin_amdgcn_mfma_f32_16x16x32_bf16(a[0], b, acc[0][nf], 0, 0, 0);
            acc[1][nf] = __builtin_amdgcn_mfma_f32_16x16x32_bf16(a[1], b, acc[1][nf], 0, 0, 0);
            acc[2][nf] = __builtin_amdgcn_mfma_f32_16x16x32_bf16(a[2], b, acc[2][nf], 0, 0, 0);
            acc[3][nf] = __builtin_amdgcn_mfma_f32_16x16x32_bf16(a[3], b, acc[3][nf], 0, 0, 0);
        }

        if (ks < 7) {
            short* dst = &bs[cur ^ 1][t * BSTRIDE];
            *(s8b*)&dst[0]  = nb0;
            *(s8b*)&dst[8]  = nb1;
            *(s8b*)&dst[16] = nb2;
            *(s8b*)&dst[24] = nb3;
        }
        __syncthreads();
        cur ^= 1;
    }

    // --- epilogue. D layout: col = ln, row = kk*4 + reg
    if (wn == 0) {
#pragma unroll
        for (int mf = 0; mf < 4; ++mf)
#pragma unroll
            for (int nf = 0; nf < 8; ++nf) {
                int col = nf * 16 + ln;
#pragma unroll
                for (int r = 0; r < 4; ++r) {
                    int nd = n0 + wm * 64 + mf * 16 + kk * 4 + r;
                    if (nd < N_NODES)
                        embh[(size_t)nd * C_DIM + col] = (ushort_t)bfc(acc[mf][nf][r]);
                }
            }
#pragma unroll
        for (int mf = 0; mf < 4; ++mf)
#pragma unroll
            for (int hh = 0; hh < HEADS; ++hh) {
                float al0 = a_l[hh * 32 + ln], al1 = a_l[hh * 32 + 16 + ln];
                float ar0 = a_r[hh * 32 + ln], ar1 = a_r[hh * 32 + 16 + ln];
#pragma unroll
                for (int r = 0; r < 4; ++r) {
                    float pl = al0 * acc[mf][2 * hh][r] + al1 * acc[mf][2 * hh + 1][r];
                    float pr = ar0 * acc[mf][2 * hh][r] + ar1 * acc[mf][2 * hh + 1][r];
#pragma unroll
                    for (int m = 8; m >= 1; m >>= 1) {
                        pl += __shfl_xor(pl, m);
                        pr += __shfl_xor(pr, m);
                    }
                    int nd = n0 + wm * 64 + mf * 16 + kk * 4 + r;
                    if (ln == 0 && nd < N_NODES) {
                        hl[nd * HEADS + hh] = pl;
                        hr[nd * HEADS + hh] = pr;
                    }
                }
            }
    } else {
#pragma unroll
        for (int mf = 0; mf < 4; ++mf)
#pragma unroll
            for (int nf = 0; nf < 8; ++nf) {
                int col = nf * 16 + ln;          // out channel
                float rb = resb[col];
#pragma unroll
                for (int r = 0; r < 4; ++r) {
                    int nd = n0 + wm * 64 + mf * 16 + kk * 4 + r;
                    if (nd < N_NODES) out[(size_t)nd * C_DIM + col] = acc[mf][nf][r] + rb;
                }
            }
    }
}

// ---------------------------------------------------------------------------
// histogram of destination degrees
__global__ void b1_hist(const int* __restrict__ col, unsigned int* __restrict__ counts) {
    int e = blockIdx.x * blockDim.x + threadIdx.x;
    if (e < N_EDGES) atomicAdd(&counts[col[e]], 1u);
}

// two-level exclusive scan
__global__ __launch_bounds__(256) void bscan1(const unsigned int* __restrict__ counts,
                                              unsigned int* __restrict__ offs,
                                              unsigned int* __restrict__ bsum) {
    __shared__ unsigned int s[256];
    int t = threadIdx.x;
    int g = blockIdx.x * 256 + t;
    unsigned int v = (g < N_NODES) ? counts[g] : 0u;
    s[t] = v;
    __syncthreads();
    for (int off = 1; off < 256; off <<= 1) {
        unsigned int x = (t >= off) ? s[t - off] : 0u;
        __syncthreads();
        s[t] += x;
        __syncthreads();
    }
    if (g < N_NODES) offs[g] = s[t] - v;
    if (t == 255) bsum[blockIdx.x] = s[255];
}

__global__ __launch_bounds__(512) void bscan2(unsigned int* __restrict__ bsum) {
    __shared__ unsigned int s[512];
    int t = threadIdx.x;
    unsigned int v = (t < NBLK_SCAN) ? bsum[t] : 0u;
    s[t] = v;
    __syncthreads();
    for (int off = 1; off < 512; off <<= 1) {
        unsigned int x = (t >= off) ? s[t - off] : 0u;
        __syncthreads();
        s[t] += x;
        __syncthreads();
    }
    if (t < NBLK_SCAN) bsum[t] = s[t] - v;
}

__global__ void bscan3(unsigned int* __restrict__ offs, const unsigned int* __restrict__ bsum,
                       unsigned int* __restrict__ cursor) {
    int g = blockIdx.x * blockDim.x + threadIdx.x;
    if (g < N_NODES) {
        unsigned int o = offs[g] + bsum[g >> 8];
        offs[g] = o;
        cursor[g] = o;
    }
    if (g == 0) offs[N_NODES] = N_EDGES;
}

// ---------------------------------------------------------------------------
// scatter: place each edge in its destination bucket.
// Stores p = exp(leaky(logit)) as 4x bf16 (softmax is shift-invariant; logits
// bounded |l|<~25 and bf16 has fp32 exponent range -> no overflow) + row idx.
__global__ void b4_scatter(const int* __restrict__ row, const int* __restrict__ col,
                           const int* __restrict__ ety,
                           const float* __restrict__ hl, const float* __restrict__ hr,
                           const float* __restrict__ het,
                           unsigned int* __restrict__ cursor,
                           uint2* __restrict__ pex, int* __restrict__ prow) {
    int e = blockIdx.x * blockDim.x + threadIdx.x;
    if (e >= N_EDGES) return;
    int r = row[e], c = col[e], ty = ety[e];
    unsigned int pos = atomicAdd(&cursor[c], 1u);
    float4 l  = *(const float4*)&hl[r * 4];
    float4 rr = *(const float4*)&hr[c * 4];
    float4 te = *(const float4*)&het[ty * 4];
    float a0 = l.x + rr.x + te.x;
    float a1 = l.y + rr.y + te.y;
    float a2 = l.z + rr.z + te.z;
    float a3 = l.w + rr.w + te.w;
    a0 = a0 > 0.f ? a0 : NEG_SLOPE * a0;
    a1 = a1 > 0.f ? a1 : NEG_SLOPE * a1;
    a2 = a2 > 0.f ? a2 : NEG_SLOPE * a2;
    a3 = a3 > 0.f ? a3 : NEG_SLOPE * a3;
    float p0 = __expf(a0), p1 = __expf(a1), p2 = __expf(a2), p3 = __expf(a3);
    unsigned int lo = ((unsigned int)(ushort_t)bfc(p0)) | (((unsigned int)(ushort_t)bfc(p1)) << 16);
    unsigned int hi = ((unsigned int)(ushort_t)bfc(p2)) | (((unsigned int)(ushort_t)bfc(p3)) << 16);
    pex[pos] = make_uint2(lo, hi);
    prow[pos] = r;
}

// ---------------------------------------------------------------------------
// fused per-node softmax-normalize + aggregation + residual + ELU.
// One wave per node. No exp / max here: p already stored, alpha = p / sum(p).
__global__ __launch_bounds__(256) void k_fused(
    const unsigned int* __restrict__ offs, const uint2* __restrict__ pex,
    const int* __restrict__ prow, const ushort_t* __restrict__ embh,
    float* __restrict__ out) {
    __shared__ float alds[4][16][4];
    __shared__ int   rlds[4][16];
    const int w    = threadIdx.x >> 6;
    const int lane = threadIdx.x & 63;
    const int c    = blockIdx.x * 4 + w;
    if (c >= N_NODES) return;

    const unsigned int start = offs[c], end = offs[c + 1];

    // phase A: sum p per head (bf16 exps unpack to fp32 adds)
    float s0 = 0.f, s1 = 0.f, s2 = 0.f, s3 = 0.f;
    for (unsigned int i = start + lane; i < end; i += 64) {
        uint2 P = pex[i];
        s0 += uasf(P.x << 16);
        s1 += uasf(P.x & 0xffff0000u);
        s2 += uasf(P.y << 16);
        s3 += uasf(P.y & 0xffff0000u);
    }
#pragma unroll
    for (int off = 32; off >= 1; off >>= 1) {
        s0 += __shfl_xor(s0, off);
        s1 += __shfl_xor(s1, off);
        s2 += __shfl_xor(s2, off);
        s3 += __shfl_xor(s3, off);
    }
    const bool hasE = end > start;
    const float i0 = hasE ? 1.f / s0 : 0.f;
    const float i1 = hasE ? 1.f / s1 : 0.f;
    const float i2 = hasE ? 1.f / s2 : 0.f;
    const float i3 = hasE ? 1.f / s3 : 0.f;

    // phase B: lane owns emb channels 2*lane, 2*lane+1 (same head h = lane>>4)
    const int hd = lane >> 4;
    float accA = 0.f, accB = 0.f;

    for (unsigned int base = start; base < end; base += 16) {
        int cnt = (int)min(16u, end - base);
        if (lane < cnt) {
            uint2 P = pex[base + lane];
            alds[w][lane][0] = uasf(P.x << 16) * i0;
            alds[w][lane][1] = uasf(P.x & 0xffff0000u) * i1;
            alds[w][lane][2] = uasf(P.y << 16) * i2;
            alds[w][lane][3] = uasf(P.y & 0xffff0000u) * i3;
            rlds[w][lane] = prow[base + lane];
        }
        for (int j = 0; j < cnt; ++j) {
            int r = rlds[w][j];
            float al = alds[w][j][hd];
            unsigned int v = *(const unsigned int*)&embh[(size_t)r * C_DIM + lane * 2];
            float lo = uasf(v << 16);
            float hi = uasf(v & 0xffff0000u);
            accA = fmaf(al, lo, accA);
            accB = fmaf(al, hi, accB);
        }
    }

    // emb channel 2*lane = hd*32 + d, d = (2*lane)&31 -> out channel d*4+hd
    const int d  = (2 * lane) & 31;
    const int oA = d * 4 + hd;
    const int oB = oA + 4;
    size_t ob = (size_t)c * C_DIM;
    float x0 = out[ob + oA] + accA;
    float x1 = out[ob + oB] + accB;
    out[ob + oA] = x0 > 0.f ? x0 : expm1f(x0);
    out[ob + oB] = x1 > 0.f ? x1 : expm1f(x1);
}

// ---------------------------------------------------------------------------
extern "C" void kernel_launch(void* const* d_in, const int* in_sizes, int n_in,
                              void* d_out, int out_size, void* d_ws, size_t ws_size,
                              hipStream_t stream) {
    const float* h        = (const float*)d_in[0];
    const float* W        = (const float*)d_in[1];
    const float* edge_emb = (const float*)d_in[2];
    const float* Wr       = (const float*)d_in[3];
    const float* a_l      = (const float*)d_in[4];
    const float* a_r      = (const float*)d_in[5];
    const float* a_e      = (const float*)d_in[6];
    const float* res_W    = (const float*)d_in[7];
    const float* res_b    = (const float*)d_in[8];
    const int*   row      = (const int*)d_in[9];
    const int*   col      = (const int*)d_in[10];
    const int*   etype    = (const int*)d_in[11];
    float* out = (float*)d_out;

    // workspace layout (4-byte units); pex first for 8B alignment
    float* ws = (float*)d_ws;
    uint2*        ws_pex   = (uint2*)ws;                                    // E*2 u32
    float*        p        = ws + (size_t)N_EDGES * 2;
    ushort_t*     ws_embh  = (ushort_t*)p;                                  // N*C_DIM shorts
    p += (size_t)N_NODES * C_DIM / 2;
    float*        ws_hl    = p;  p += (size_t)N_NODES * HEADS;              // N*4
    float*        ws_hr    = p;  p += (size_t)N_NODES * HEADS;              // N*4
    float*        ws_het   = p;  p += 32;
    unsigned int* ws_offs  = (unsigned int*)p;                              // N+1
    unsigned int* ws_cur   = ws_offs + (N_NODES + 1);                       // N
    unsigned int* ws_cnt   = ws_cur + N_NODES;                              // N
    unsigned int* ws_bsum  = ws_cnt + N_NODES;                              // NBLK_SCAN
    int*          ws_prow  = (int*)(ws_bsum + NBLK_SCAN);                   // E
    short*        ws_wt    = (short*)(ws_prow + N_EDGES);                   // 256*256 bf16

    kz_init<<<(N_NODES + 255) / 256, 256, 0, stream>>>(ws_cnt);

    k_het<<<NUM_ETY, 256, 0, stream>>>(edge_emb, Wr, a_e, ws_het);

    kw_prep<<<256, 256, 0, stream>>>(W, res_W, ws_wt);

    k1_mfma<<<(N_NODES + M_TILE - 1) / M_TILE, 256, 0, stream>>>(
        h, ws_wt, res_b, a_l, a_r, ws_embh, ws_hl, ws_hr, out);

    b1_hist<<<(N_EDGES + 255) / 256, 256, 0, stream>>>(col, ws_cnt);

    bscan1<<<NBLK_SCAN, 256, 0, stream>>>(ws_cnt, ws_offs, ws_bsum);
    bscan2<<<1, 512, 0, stream>>>(ws_bsum);
    bscan3<<<(N_NODES + 255) / 256, 256, 0, stream>>>(ws_offs, ws_bsum, ws_cur);

    b4_scatter<<<(N_EDGES + 255) / 256, 256, 0, stream>>>(
        row, col, etype, ws_hl, ws_hr, ws_het, ws_cur, ws_pex, ws_prow);

    k_fused<<<(N_NODES + 3) / 4, 256, 0, stream>>>(
        ws_offs, ws_pex, ws_prow, ws_embh, out);
}